// Round 10
// baseline (1296.522 us; speedup 1.0000x reference)
//
#include <hip/hip_runtime.h>
#include <math.h>

// RALALinearAttention on MI355X — round 10.
// r9: B-direct-from-global regressed GEMM (16B/lane 512B-stride gathers,
// FETCH 74->133MB). Revert GEMM to r7's proven 90us structure.
// Main change: k_fused_stats — one block per (b,h) fusing qmean -> scores ->
// softmax -> kmean+kv(+eff,rope) (8 dispatches -> 1, kills eff/kvp/part bufs).
constexpr int B   = 16;
constexpr int IH  = 64;
constexpr int IW  = 64;
constexpr int C   = 256;
constexpr int NH  = 8;
constexpr int HD  = 32;
constexpr int N   = IH * IW;    // 4096
constexpr int C4  = 4 * C;      // 1024

using f16x8 = __attribute__((ext_vector_type(8))) _Float16;
using f32x4 = __attribute__((ext_vector_type(4))) float;

// ---------------------------------------------------------------- tables ----
__global__ void k_tables(float* __restrict__ cosT, float* __restrict__ sinT) {
  int t = blockIdx.x * 256 + threadIdx.x;      // N*16 = 65536
  int j = t & 15, pix = t >> 4;
  int y = pix >> 6, x = pix & 63;
  int jj = j & 7;
  double theta = pow(10000.0, -(double)jj / 8.0);
  double pos = (j < 8) ? (double)y : (double)x;
  double ang = pos * theta;
  cosT[t] = (float)cos(ang);
  sinT[t] = (float)sin(ang);
}

// ------------- split weight [K=256][ldb] -> transposed [ldb][256] -----------
__global__ void k_split_wT(const float* __restrict__ w, int ldb,
                           _Float16* __restrict__ hiT, _Float16* __restrict__ loT) {
  int n = blockIdx.x;           // column of w
  int k = threadIdx.x;          // 0..255
  float v = w[(size_t)k * ldb + n];
  _Float16 h = (_Float16)v;
  hiT[(size_t)n * 256 + k] = h;
  loT[(size_t)n * 256 + k] = (_Float16)(v - (float)h);
}

// --------------- split-f16 MFMA GEMM (r7 structure, 90us proven) ------------
// 128x128 tile, 4 waves (2x2), K=256, BK=32, 3-product Ootomo split.
// A: f32, split in staging (cvt overlaps MFMA via reg-prefetch pipeline).
// B: preconverted transposed splits [N][256], staged via LDS.
__global__ __launch_bounds__(256) void k_gemm_split(
    const float* __restrict__ A, int lda,
    const _Float16* __restrict__ BhT, const _Float16* __restrict__ BlT,
    const float* __restrict__ bias, float* __restrict__ Cm, int ldc,
    int nelu) {
  __shared__ _Float16 lds[4 * 5120];          // Ah | Al | Bh | Bl, stride 40
  _Float16* AhL = lds;
  _Float16* AlL = lds + 5120;
  _Float16* BhL = lds + 10240;
  _Float16* BlL = lds + 15360;
  int t = threadIdx.x;
  int m0 = blockIdx.x * 128, n0 = blockIdx.y * 128;
  int lane = t & 63;
  int wm = t >> 7, wn = (t >> 6) & 1;
  int lr = lane & 15, lg = lane >> 4;
  int srow = t >> 1, sseg = t & 1;            // one row-half per thread

  f32x4 acc[4][4] = {};

  const float* aP = &A[(size_t)(m0 + srow) * lda + sseg * 16];
  const _Float16* bhP = &BhT[(size_t)(n0 + srow) * 256 + sseg * 16];
  const _Float16* blP = &BlT[(size_t)(n0 + srow) * 256 + sseg * 16];
  float4 ar0 = *(const float4*)(aP + 0);
  float4 ar1 = *(const float4*)(aP + 4);
  float4 ar2 = *(const float4*)(aP + 8);
  float4 ar3 = *(const float4*)(aP + 12);
  f16x8 brh0 = *(const f16x8*)(bhP + 0);
  f16x8 brh1 = *(const f16x8*)(bhP + 8);
  f16x8 brl0 = *(const f16x8*)(blP + 0);
  f16x8 brl1 = *(const f16x8*)(blP + 8);

  for (int kc = 0; kc < 256; kc += 32) {
    {
      float av[16] = {ar0.x, ar0.y, ar0.z, ar0.w, ar1.x, ar1.y, ar1.z, ar1.w,
                      ar2.x, ar2.y, ar2.z, ar2.w, ar3.x, ar3.y, ar3.z, ar3.w};
      f16x8 h0, h1, l0, l1;
#pragma unroll
      for (int j = 0; j < 8; ++j) {
        _Float16 h = (_Float16)av[j];
        h0[j] = h; l0[j] = (_Float16)(av[j] - (float)h);
        _Float16 h2 = (_Float16)av[j + 8];
        h1[j] = h2; l1[j] = (_Float16)(av[j + 8] - (float)h2);
      }
      int d = srow * 40 + sseg * 16;
      *(f16x8*)&AhL[d] = h0; *(f16x8*)&AhL[d + 8] = h1;
      *(f16x8*)&AlL[d] = l0; *(f16x8*)&AlL[d + 8] = l1;
      *(f16x8*)&BhL[d] = brh0; *(f16x8*)&BhL[d + 8] = brh1;
      *(f16x8*)&BlL[d] = brl0; *(f16x8*)&BlL[d + 8] = brl1;
    }
    __syncthreads();

    if (kc + 32 < 256) {
      const float* aN = aP + kc + 32;
      const _Float16* bhN = bhP + kc + 32;
      const _Float16* blN = blP + kc + 32;
      ar0 = *(const float4*)(aN + 0);
      ar1 = *(const float4*)(aN + 4);
      ar2 = *(const float4*)(aN + 8);
      ar3 = *(const float4*)(aN + 12);
      brh0 = *(const f16x8*)(bhN + 0);
      brh1 = *(const f16x8*)(bhN + 8);
      brl0 = *(const f16x8*)(blN + 0);
      brl1 = *(const f16x8*)(blN + 8);
    }

    f16x8 ah[4], al[4];
#pragma unroll
    for (int mi = 0; mi < 4; ++mi) {
      int ar = (wm * 64 + mi * 16 + lr) * 40 + lg * 8;
      ah[mi] = *(const f16x8*)&AhL[ar];
      al[mi] = *(const f16x8*)&AlL[ar];
    }
#pragma unroll
    for (int ni = 0; ni < 4; ++ni) {
      int br = (wn * 64 + ni * 16 + lr) * 40 + lg * 8;
      f16x8 bh = *(const f16x8*)&BhL[br];
      f16x8 bl = *(const f16x8*)&BlL[br];
#pragma unroll
      for (int mi = 0; mi < 4; ++mi) {
        acc[mi][ni] = __builtin_amdgcn_mfma_f32_16x16x32_f16(ah[mi], bh, acc[mi][ni], 0, 0, 0);
        acc[mi][ni] = __builtin_amdgcn_mfma_f32_16x16x32_f16(al[mi], bh, acc[mi][ni], 0, 0, 0);
        acc[mi][ni] = __builtin_amdgcn_mfma_f32_16x16x32_f16(ah[mi], bl, acc[mi][ni], 0, 0, 0);
      }
    }
    __syncthreads();
  }

  // ---- epilogue: LDS transpose -> coalesced float4 stores ----
  float* Cl = reinterpret_cast<float*>(lds);   // 32 x 132 f32
  int ri2 = t >> 3, c0 = (t & 7) << 4;
#pragma unroll
  for (int mi = 0; mi < 4; ++mi) {
#pragma unroll
    for (int ni = 0; ni < 4; ++ni) {
      int col = wn * 64 + ni * 16 + lr;
#pragma unroll
      for (int r = 0; r < 4; ++r)
        Cl[(wm * 16 + lg * 4 + r) * 132 + col] = acc[mi][ni][r];
    }
    __syncthreads();
    int grow = m0 + (ri2 >> 4) * 64 + mi * 16 + (ri2 & 15);
#pragma unroll
    for (int j = 0; j < 4; ++j) {
      int col = n0 + c0 + j * 4;
      float4 v = *(const float4*)&Cl[ri2 * 132 + c0 + j * 4];
      float4 bb = *(const float4*)&bias[col];
      v.x += bb.x; v.y += bb.y; v.z += bb.z; v.w += bb.w;
      if (col < nelu) {
        v.x = (v.x > 0.f) ? v.x + 1.f : expf(v.x);
        v.y = (v.y > 0.f) ? v.y + 1.f : expf(v.y);
        v.z = (v.z > 0.f) ? v.z + 1.f : expf(v.z);
        v.w = (v.w > 0.f) ? v.w + 1.f : expf(v.w);
      }
      *(float4*)&Cm[(size_t)grow * ldc + col] = v;
    }
    __syncthreads();
  }
}

// ---- fused per-(b,h) stats: qmean -> scores -> softmax -> kmean + kv -------
// one block per (b,h). kvkm: per bh, 1024 kv + 32 kmean.
__global__ __launch_bounds__(256) void k_fused_stats(
    const float* __restrict__ qkvo, const float* __restrict__ cosT,
    const float* __restrict__ sinT, float* __restrict__ kvkm) {
  __shared__ float s_row[N];       // 16 KiB: scores -> effN
  __shared__ float red[256];
  __shared__ float qmean[32];
  __shared__ float kt[32][33];
  __shared__ float vt[32][33];
  __shared__ float kmp[32][32];
  int bh = blockIdx.x;
  int b = bh >> 3, h = bh & 7;
  int t = threadIdx.x;
  const float* qb = qkvo + (size_t)b * N * C4 + (h << 5);
  const float* kb = qb + 256;
  const float* vb = qb + 512;

  // phase 1: qmean (fold softmax scale 1/sqrt(32))
  {
    int d = t & 31, r = t >> 5;
    float acc = 0.f;
    for (int n = r; n < N; n += 8) acc += qb[(size_t)n * C4 + d];
    red[t] = acc;
    __syncthreads();
    if (t < 32) {
      float s = 0.f;
#pragma unroll
      for (int rr = 0; rr < 8; ++rr) s += red[rr * 32 + t];
      qmean[t] = s * (1.0f / N) * 0.1767766952966369f;
    }
    __syncthreads();
  }
  // phase 2: scores
  {
    float qm[32];
#pragma unroll
    for (int i = 0; i < 32; ++i) qm[i] = qmean[i];
#pragma unroll
    for (int i = 0; i < 16; ++i) {
      int n = t + i * 256;
      const float* kp = kb + (size_t)n * C4;
      float dot = 0.f;
#pragma unroll
      for (int j = 0; j < 8; ++j) {
        float4 k4 = *(const float4*)(kp + j * 4);
        dot += k4.x * qm[j*4] + k4.y * qm[j*4+1] + k4.z * qm[j*4+2] + k4.w * qm[j*4+3];
      }
      s_row[n] = dot;
    }
    __syncthreads();
  }
  // phase 3: softmax over s_row, fold *N
  {
    float mx = -3.4e38f;
#pragma unroll
    for (int i = 0; i < 16; ++i) mx = fmaxf(mx, s_row[t + i * 256]);
    red[t] = mx; __syncthreads();
    for (int off = 128; off > 0; off >>= 1) {
      if (t < off) red[t] = fmaxf(red[t], red[t + off]);
      __syncthreads();
    }
    mx = red[0]; __syncthreads();
    float sum = 0.f;
#pragma unroll
    for (int i = 0; i < 16; ++i) {
      int n = t + i * 256;
      float e = expf(s_row[n] - mx);
      s_row[n] = e;
      sum += e;
    }
    red[t] = sum; __syncthreads();
    for (int off = 128; off > 0; off >>= 1) {
      if (t < off) red[t] += red[t + off];
      __syncthreads();
    }
    float scale = (float)N / red[0];
    __syncthreads();
#pragma unroll
    for (int i = 0; i < 16; ++i) s_row[t + i * 256] *= scale;
    __syncthreads();
  }
  // phase 4: kmean + kv (eff*k, rope(k) fused)
  {
    int lrow = t >> 3, lc4 = (t & 7) << 2;
    int d = t >> 3, e0 = (t & 7) << 2;
    float a0 = 0, a1 = 0, a2 = 0, a3 = 0;
    float km0 = 0, km1 = 0, km2 = 0, km3 = 0;
    for (int n0 = 0; n0 < N; n0 += 32) {
      int n = n0 + lrow;
      size_t g = (size_t)n * C4;
      float4 k4 = *(const float4*)(kb + g + lc4);
      float4 v4 = *(const float4*)(vb + g + lc4);
      float ef = s_row[n];
      k4.x *= ef; k4.y *= ef; k4.z *= ef; k4.w *= ef;
      km0 += k4.x; km1 += k4.y; km2 += k4.z; km3 += k4.w;
      float2 cc = *(const float2*)(cosT + (n << 4) + (lc4 >> 1));
      float2 ss = *(const float2*)(sinT + (n << 4) + (lc4 >> 1));
      kt[lrow][lc4 + 0] = k4.x * cc.x - k4.y * ss.x;
      kt[lrow][lc4 + 1] = k4.x * ss.x + k4.y * cc.x;
      kt[lrow][lc4 + 2] = k4.z * cc.y - k4.w * ss.y;
      kt[lrow][lc4 + 3] = k4.z * ss.y + k4.w * cc.y;
      vt[lrow][lc4 + 0] = v4.x; vt[lrow][lc4 + 1] = v4.y;
      vt[lrow][lc4 + 2] = v4.z; vt[lrow][lc4 + 3] = v4.w;
      __syncthreads();
#pragma unroll
      for (int nn = 0; nn < 32; ++nn) {
        float kd = kt[nn][d];
        a0 = fmaf(kd, vt[nn][e0 + 0], a0);
        a1 = fmaf(kd, vt[nn][e0 + 1], a1);
        a2 = fmaf(kd, vt[nn][e0 + 2], a2);
        a3 = fmaf(kd, vt[nn][e0 + 3], a3);
      }
      __syncthreads();
    }
    size_t o = (size_t)bh * 1056;
    float inv = 1.0f / N;
    kvkm[o + (d << 5) + e0 + 0] = a0 * inv;
    kvkm[o + (d << 5) + e0 + 1] = a1 * inv;
    kvkm[o + (d << 5) + e0 + 2] = a2 * inv;
    kvkm[o + (d << 5) + e0 + 3] = a3 * inv;
    kmp[lrow][lc4 + 0] = km0; kmp[lrow][lc4 + 1] = km1;
    kmp[lrow][lc4 + 2] = km2; kmp[lrow][lc4 + 3] = km3;
    __syncthreads();
    if (t < 32) {
      float s = 0.f;
#pragma unroll
      for (int rr = 0; rr < 32; ++rr) s += kmp[rr][t];
      kvkm[o + 1024 + t] = s * inv;
    }
  }
}

// -------- depthwise 5x5 conv on v (LEPE) -> staged into d_out rows ----------
__global__ __launch_bounds__(256) void k_lepe(
    const float* __restrict__ qkvo, const float* __restrict__ wgt,
    const float* __restrict__ lb, float* __restrict__ lepe_out, int b0) {
  int blk = blockIdx.x;                        // bpp*64*4
  int b = blk >> 8, rem = blk & 255;
  int y = rem >> 2, x0 = (rem & 3) << 4;       // 16 pixels along x
  int c = threadIdx.x;
  float w[25];
#pragma unroll
  for (int i = 0; i < 25; ++i) w[i] = wgt[c * 25 + i];
  float bias = lb[c];
  float acc[16];
#pragma unroll
  for (int p = 0; p < 16; ++p) acc[p] = bias;
#pragma unroll
  for (int dy = 0; dy < 5; ++dy) {
    int yy = y + dy - 2;
    if (yy < 0 || yy >= IH) continue;
    size_t rowb = (size_t)(b * N + (yy << 6)) * C4 + 512 + c;
#pragma unroll
    for (int dx = 0; dx < 5; ++dx) {
      float wv = w[dy * 5 + dx];
#pragma unroll
      for (int p = 0; p < 16; ++p) {
        int xx = x0 + p + dx - 2;
        if (xx < 0 || xx >= IW) continue;
        acc[p] = fmaf(qkvo[rowb + (size_t)xx * C4], wv, acc[p]);
      }
    }
  }
#pragma unroll
  for (int p = 0; p < 16; ++p)
    lepe_out[(size_t)((b0 + b) * N + (y << 6) + x0 + p) * C + c] = acc[p];
}

// -- opre = ((rope(q) @ kv) * z + lepe) * o, z = 1/(q.kmean+eps), in place ---
__global__ __launch_bounds__(256) void k_out_combine(
    float* __restrict__ qkvo, const float* __restrict__ kvkm,
    const float* __restrict__ cosT, const float* __restrict__ sinT,
    const float* __restrict__ lepe, int b0) {
  __shared__ float kvs[1024];
  __shared__ float kms[32];
  int bh = blockIdx.x, chunk = blockIdx.y;
  int b = bh >> 3, h = bh & 7;
  int t = threadIdx.x;
  reinterpret_cast<float4*>(kvs)[t] =
      reinterpret_cast<const float4*>(&kvkm[(size_t)bh * 1056])[t];
  if (t < 32) kms[t] = kvkm[(size_t)bh * 1056 + 1024 + t];
  __syncthreads();
  int n = (chunk << 8) + t;
  size_t rowbase = (size_t)(b * N + n) * C4;
  float q[32];
#pragma unroll
  for (int i = 0; i < 8; ++i) {
    float4 q4 = *reinterpret_cast<const float4*>(&qkvo[rowbase + (h << 5) + (i << 2)]);
    q[i * 4 + 0] = q4.x; q[i * 4 + 1] = q4.y; q[i * 4 + 2] = q4.z; q[i * 4 + 3] = q4.w;
  }
  float dot = 0.f;
#pragma unroll
  for (int dd = 0; dd < 32; ++dd) dot += q[dd] * kms[dd];
  float zv = 1.0f / (dot + 1e-6f);
  const float* cp = &cosT[n << 4];
  const float* sp = &sinT[n << 4];
#pragma unroll
  for (int j = 0; j < 16; ++j) {
    float cc = cp[j], ss = sp[j];
    float qr = q[2 * j], qi = q[2 * j + 1];
    q[2 * j]     = qr * cc - qi * ss;
    q[2 * j + 1] = qr * ss + qi * cc;
  }
  size_t oc = (size_t)((b0 + b) * N + n) * C + (h << 5);   // lepe rows in d_out
#pragma unroll
  for (int e4 = 0; e4 < 8; ++e4) {
    float ax = 0, ay = 0, az = 0, aw = 0;
#pragma unroll
    for (int dd = 0; dd < 32; ++dd) {
      float4 kv4 = *reinterpret_cast<const float4*>(&kvs[(dd << 5) + (e4 << 2)]);
      float qd = q[dd];
      ax = fmaf(qd, kv4.x, ax); ay = fmaf(qd, kv4.y, ay);
      az = fmaf(qd, kv4.z, az); aw = fmaf(qd, kv4.w, aw);
    }
    float4 lp = *reinterpret_cast<const float4*>(&lepe[oc + (e4 << 2)]);
    float4 ov = *reinterpret_cast<const float4*>(
        &qkvo[rowbase + 768 + (h << 5) + (e4 << 2)]);
    float4 r;
    r.x = (ax * zv + lp.x) * ov.x;
    r.y = (ay * zv + lp.y) * ov.y;
    r.z = (az * zv + lp.z) * ov.z;
    r.w = (aw * zv + lp.w) * ov.w;
    *reinterpret_cast<float4*>(&qkvo[rowbase + (h << 5) + (e4 << 2)]) = r;
  }
}

// ---------------------------------------------------------------------------
static inline size_t ws_bytes_needed(int bpp) {
  size_t pn = (size_t)bpp * N;
  size_t f32c = pn * C4                       // qkvo
              + (size_t)bpp * NH * 1056       // kv + kmean
              + (size_t)N * 16 * 2;           // cos/sin
  size_t f16c = (size_t)C * C4 * 2            // wq T splits
              + (size_t)C * C * 2;            // wp T splits
  return f32c * 4 + f16c * 2;
}

extern "C" void kernel_launch(void* const* d_in, const int* in_sizes, int n_in,
                              void* d_out, int out_size, void* d_ws, size_t ws_size,
                              hipStream_t stream) {
  const float* x      = (const float*)d_in[0];
  const float* w_qkvo = (const float*)d_in[1];
  const float* b_qkvo = (const float*)d_in[2];
  const float* lepe_w = (const float*)d_in[3];
  const float* lepe_b = (const float*)d_in[4];
  const float* w_proj = (const float*)d_in[5];
  const float* b_proj = (const float*)d_in[6];
  float* out = (float*)d_out;
  float* ws  = (float*)d_ws;

  int bpp = 2;
  if (ws_bytes_needed(16) <= ws_size) bpp = 16;
  else if (ws_bytes_needed(8) <= ws_size) bpp = 8;
  else if (ws_bytes_needed(4) <= ws_size) bpp = 4;

  size_t pn = (size_t)bpp * N;
  float* qkvo  = ws;
  float* kvkm  = qkvo  + pn * C4;
  float* cosT  = kvkm  + (size_t)bpp * NH * 1056;
  float* sinT  = cosT  + (size_t)N * 16;
  _Float16* wqh = (_Float16*)(sinT + (size_t)N * 16);
  _Float16* wql = wqh + (size_t)C * C4;
  _Float16* wph = wql + (size_t)C * C4;
  _Float16* wpl = wph + (size_t)C * C;

  k_tables<<<N * 16 / 256, 256, 0, stream>>>(cosT, sinT);
  k_split_wT<<<C4, 256, 0, stream>>>(w_qkvo, C4, wqh, wql);
  k_split_wT<<<C, 256, 0, stream>>>(w_proj, C, wph, wpl);

  int nbh = bpp * NH;
  for (int b0 = 0; b0 < B; b0 += bpp) {
    // GEMM1: qkvo = x@w_qkvo + b, elu on cols<512
    k_gemm_split<<<dim3(pn / 128, C4 / 128), 256, 0, stream>>>(
        x + (size_t)b0 * N * C, C, wqh, wql, b_qkvo, qkvo, C4, 512);
    // fused stats: qmean -> scores -> softmax -> kmean + kv
    k_fused_stats<<<nbh, 256, 0, stream>>>(qkvo, cosT, sinT, kvkm);
    k_lepe<<<bpp * IH * 4, 256, 0, stream>>>(qkvo, lepe_w, lepe_b, out, b0);
    k_out_combine<<<dim3(nbh, 16), 256, 0, stream>>>(qkvo, kvkm, cosT, sinT, out, b0);
    // GEMM2: out = opre @ w_proj + b (A = f32 opre in qkvo q-slot)
    k_gemm_split<<<dim3(pn / 128, C / 128), 256, 0, stream>>>(
        qkvo, C4, wph, wpl, b_proj, out + (size_t)b0 * N * C, C, 0);
  }
}

// Round 11
// 576.641 us; speedup vs baseline: 2.2484x; 2.2484x over previous
//
#include <hip/hip_runtime.h>
#include <math.h>

// RALALinearAttention on MI355X — round 11.
// r10 lesson: fusing the stats chain into 64 blocks (1 per (b,h)) collapsed
// occupancy to 3% -> 416us. Fuse WITHOUT shrinking grids instead:
//  - qmean partials computed in GEMM1's epilogue (block-local LDS reduce).
//  - kmean partials computed inside kv_partial (it already reads eff*k).
//  - softmax -> stats-only (mx, N/sum); consumers exp() inline.
// GEMM: r7's proven 90us structure.
constexpr int B   = 16;
constexpr int IH  = 64;
constexpr int IW  = 64;
constexpr int C   = 256;
constexpr int NH  = 8;
constexpr int HD  = 32;
constexpr int N   = IH * IW;    // 4096
constexpr int C4  = 4 * C;      // 1024

using f16x8 = __attribute__((ext_vector_type(8))) _Float16;
using f32x4 = __attribute__((ext_vector_type(4))) float;

// ---------------------------------------------------------------- tables ----
__global__ void k_tables(float* __restrict__ cosT, float* __restrict__ sinT) {
  int t = blockIdx.x * 256 + threadIdx.x;      // N*16 = 65536
  int j = t & 15, pix = t >> 4;
  int y = pix >> 6, x = pix & 63;
  int jj = j & 7;
  double theta = pow(10000.0, -(double)jj / 8.0);
  double pos = (j < 8) ? (double)y : (double)x;
  double ang = pos * theta;
  cosT[t] = (float)cos(ang);
  sinT[t] = (float)sin(ang);
}

// ------------- split weight [K=256][ldb] -> transposed [ldb][256] -----------
__global__ void k_split_wT(const float* __restrict__ w, int ldb,
                           _Float16* __restrict__ hiT, _Float16* __restrict__ loT) {
  int n = blockIdx.x;           // column of w
  int k = threadIdx.x;          // 0..255
  float v = w[(size_t)k * ldb + n];
  _Float16 h = (_Float16)v;
  hiT[(size_t)n * 256 + k] = h;
  loT[(size_t)n * 256 + k] = (_Float16)(v - (float)h);
}

// --------------- split-f16 MFMA GEMM (r7 structure) + qmean partials --------
// 128x128 tile, 4 waves (2x2), K=256, BK=32, 3-product Ootomo split.
// If qpart != nullptr, blocks with n0<256 also emit per-block column sums of
// the post-elu output (qmean partials), layout [b_local*32+rowblk][256].
__global__ __launch_bounds__(256) void k_gemm_split(
    const float* __restrict__ A, int lda,
    const _Float16* __restrict__ BhT, const _Float16* __restrict__ BlT,
    const float* __restrict__ bias, float* __restrict__ Cm, int ldc,
    int nelu, float* __restrict__ qpart) {
  __shared__ _Float16 lds[4 * 5120];          // Ah | Al | Bh | Bl, stride 40
  _Float16* AhL = lds;
  _Float16* AlL = lds + 5120;
  _Float16* BhL = lds + 10240;
  _Float16* BlL = lds + 15360;
  int t = threadIdx.x;
  int m0 = blockIdx.x * 128, n0 = blockIdx.y * 128;
  int lane = t & 63;
  int wm = t >> 7, wn = (t >> 6) & 1;
  int lr = lane & 15, lg = lane >> 4;
  int srow = t >> 1, sseg = t & 1;            // one row-half per thread

  f32x4 acc[4][4] = {};

  const float* aP = &A[(size_t)(m0 + srow) * lda + sseg * 16];
  const _Float16* bhP = &BhT[(size_t)(n0 + srow) * 256 + sseg * 16];
  const _Float16* blP = &BlT[(size_t)(n0 + srow) * 256 + sseg * 16];
  float4 ar0 = *(const float4*)(aP + 0);
  float4 ar1 = *(const float4*)(aP + 4);
  float4 ar2 = *(const float4*)(aP + 8);
  float4 ar3 = *(const float4*)(aP + 12);
  f16x8 brh0 = *(const f16x8*)(bhP + 0);
  f16x8 brh1 = *(const f16x8*)(bhP + 8);
  f16x8 brl0 = *(const f16x8*)(blP + 0);
  f16x8 brl1 = *(const f16x8*)(blP + 8);

  for (int kc = 0; kc < 256; kc += 32) {
    {
      float av[16] = {ar0.x, ar0.y, ar0.z, ar0.w, ar1.x, ar1.y, ar1.z, ar1.w,
                      ar2.x, ar2.y, ar2.z, ar2.w, ar3.x, ar3.y, ar3.z, ar3.w};
      f16x8 h0, h1, l0, l1;
#pragma unroll
      for (int j = 0; j < 8; ++j) {
        _Float16 h = (_Float16)av[j];
        h0[j] = h; l0[j] = (_Float16)(av[j] - (float)h);
        _Float16 h2 = (_Float16)av[j + 8];
        h1[j] = h2; l1[j] = (_Float16)(av[j + 8] - (float)h2);
      }
      int d = srow * 40 + sseg * 16;
      *(f16x8*)&AhL[d] = h0; *(f16x8*)&AhL[d + 8] = h1;
      *(f16x8*)&AlL[d] = l0; *(f16x8*)&AlL[d + 8] = l1;
      *(f16x8*)&BhL[d] = brh0; *(f16x8*)&BhL[d + 8] = brh1;
      *(f16x8*)&BlL[d] = brl0; *(f16x8*)&BlL[d + 8] = brl1;
    }
    __syncthreads();

    if (kc + 32 < 256) {
      const float* aN = aP + kc + 32;
      const _Float16* bhN = bhP + kc + 32;
      const _Float16* blN = blP + kc + 32;
      ar0 = *(const float4*)(aN + 0);
      ar1 = *(const float4*)(aN + 4);
      ar2 = *(const float4*)(aN + 8);
      ar3 = *(const float4*)(aN + 12);
      brh0 = *(const f16x8*)(bhN + 0);
      brh1 = *(const f16x8*)(bhN + 8);
      brl0 = *(const f16x8*)(blN + 0);
      brl1 = *(const f16x8*)(blN + 8);
    }

    f16x8 ah[4], al[4];
#pragma unroll
    for (int mi = 0; mi < 4; ++mi) {
      int ar = (wm * 64 + mi * 16 + lr) * 40 + lg * 8;
      ah[mi] = *(const f16x8*)&AhL[ar];
      al[mi] = *(const f16x8*)&AlL[ar];
    }
#pragma unroll
    for (int ni = 0; ni < 4; ++ni) {
      int br = (wn * 64 + ni * 16 + lr) * 40 + lg * 8;
      f16x8 bh = *(const f16x8*)&BhL[br];
      f16x8 bl = *(const f16x8*)&BlL[br];
#pragma unroll
      for (int mi = 0; mi < 4; ++mi) {
        acc[mi][ni] = __builtin_amdgcn_mfma_f32_16x16x32_f16(ah[mi], bh, acc[mi][ni], 0, 0, 0);
        acc[mi][ni] = __builtin_amdgcn_mfma_f32_16x16x32_f16(al[mi], bh, acc[mi][ni], 0, 0, 0);
        acc[mi][ni] = __builtin_amdgcn_mfma_f32_16x16x32_f16(ah[mi], bl, acc[mi][ni], 0, 0, 0);
      }
    }
    __syncthreads();
  }

  // ---- epilogue: LDS transpose -> coalesced float4 stores (+ qmean qs) ----
  float* Cl = reinterpret_cast<float*>(lds);   // 32 x 132 f32
  int ri2 = t >> 3, c0 = (t & 7) << 4;
  bool doq = (qpart != nullptr) && (n0 < 256);  // block-uniform
  float qs[16] = {};
#pragma unroll
  for (int mi = 0; mi < 4; ++mi) {
#pragma unroll
    for (int ni = 0; ni < 4; ++ni) {
      int col = wn * 64 + ni * 16 + lr;
#pragma unroll
      for (int r = 0; r < 4; ++r)
        Cl[(wm * 16 + lg * 4 + r) * 132 + col] = acc[mi][ni][r];
    }
    __syncthreads();
    int grow = m0 + (ri2 >> 4) * 64 + mi * 16 + (ri2 & 15);
#pragma unroll
    for (int j = 0; j < 4; ++j) {
      int col = n0 + c0 + j * 4;
      float4 v = *(const float4*)&Cl[ri2 * 132 + c0 + j * 4];
      float4 bb = *(const float4*)&bias[col];
      v.x += bb.x; v.y += bb.y; v.z += bb.z; v.w += bb.w;
      if (col < nelu) {
        v.x = (v.x > 0.f) ? v.x + 1.f : expf(v.x);
        v.y = (v.y > 0.f) ? v.y + 1.f : expf(v.y);
        v.z = (v.z > 0.f) ? v.z + 1.f : expf(v.z);
        v.w = (v.w > 0.f) ? v.w + 1.f : expf(v.w);
      }
      if (doq) {
        qs[j * 4 + 0] += v.x; qs[j * 4 + 1] += v.y;
        qs[j * 4 + 2] += v.z; qs[j * 4 + 3] += v.w;
      }
      *(float4*)&Cm[(size_t)grow * ldc + col] = v;
    }
    __syncthreads();
  }
  if (doq) {
    // per-thread qs covers cols c0..c0+15 over its 4 rows; reduce 32 ri2 rows
#pragma unroll
    for (int j = 0; j < 4; ++j) {
      float4 w4 = {qs[j*4+0], qs[j*4+1], qs[j*4+2], qs[j*4+3]};
      *(float4*)&Cl[ri2 * 132 + c0 + j * 4] = w4;
    }
    __syncthreads();
    if (t < 128) {
      float ssum = 0.f;
#pragma unroll
      for (int rr = 0; rr < 32; ++rr) ssum += Cl[rr * 132 + t];
      int b_local = m0 >> 12, rowblk = (m0 >> 7) & 31;
      qpart[(size_t)(b_local * 32 + rowblk) * 256 + n0 + t] = ssum;
    }
  }
}

// ------- qmean finalize: reduce 32 rowblock partials, fold invN*scale -------
__global__ void k_qmean_fin(const float* __restrict__ qpart,
                            float* __restrict__ qmean, int total) {
  int i = blockIdx.x * 256 + threadIdx.x;      // nbh*32
  if (i >= total) return;
  int bh = i >> 5, d = i & 31;
  int b = bh >> 3, h = bh & 7;
  float s = 0.f;
#pragma unroll
  for (int rb = 0; rb < 32; ++rb)
    s += qpart[(size_t)(b * 32 + rb) * 256 + (h << 5) + d];
  qmean[i] = s * (1.0f / N) * 0.1767766952966369f;
}

// ------------------------------------------- scores s = qmean_scaled . k ----
__global__ void k_scores(const float* __restrict__ qkvo,
                         const float* __restrict__ qmean, float* __restrict__ s) {
  int tid = blockIdx.x * 256 + threadIdx.x;   // nbh*N
  int n = tid & (N - 1);
  int bh = tid >> 12;
  int b = bh >> 3, h = bh & 7;
  const float* kp = &qkvo[(size_t)(b * N + n) * C4 + 256 + (h << 5)];
  const float* qm = &qmean[bh << 5];
  float dot = 0.f;
#pragma unroll
  for (int i = 0; i < 8; ++i) {
    float4 k4 = *reinterpret_cast<const float4*>(&kp[i << 2]);
    float4 q4 = *reinterpret_cast<const float4*>(&qm[i << 2]);
    dot += k4.x * q4.x + k4.y * q4.y + k4.z * q4.z + k4.w * q4.w;
  }
  s[tid] = dot;
}

// ------------- softmax stats only: mx and N/sum per (b,h) -------------------
__global__ __launch_bounds__(256) void k_smstats(const float* __restrict__ s,
                                                 float* __restrict__ smst) {
  __shared__ float rowl[N];
  __shared__ float red[256];
  int bh = blockIdx.x;
  int t = threadIdx.x;
  const float* row = s + (size_t)bh * N;
  float mx = -3.4e38f;
  for (int i = t; i < N / 4; i += 256) {
    float4 v = reinterpret_cast<const float4*>(row)[i];
    reinterpret_cast<float4*>(rowl)[i] = v;
    mx = fmaxf(mx, fmaxf(fmaxf(v.x, v.y), fmaxf(v.z, v.w)));
  }
  red[t] = mx; __syncthreads();
  for (int off = 128; off > 0; off >>= 1) {
    if (t < off) red[t] = fmaxf(red[t], red[t + off]);
    __syncthreads();
  }
  mx = red[0]; __syncthreads();
  float sum = 0.f;
  for (int n = t; n < N; n += 256) sum += expf(rowl[n] - mx);
  red[t] = sum; __syncthreads();
  for (int off = 128; off > 0; off >>= 1) {
    if (t < off) red[t] += red[t + off];
    __syncthreads();
  }
  if (t == 0) {
    smst[bh * 2 + 0] = mx;
    smst[bh * 2 + 1] = (float)N / red[0];
  }
}

// -- kv+km partials: eff inline (exp), rope(k) fused; grid (nbh, 8 chunks) ---
__global__ __launch_bounds__(256) void k_kvkm_partial(
    const float* __restrict__ qkvo, const float* __restrict__ s,
    const float* __restrict__ smst, const float* __restrict__ cosT,
    const float* __restrict__ sinT, float* __restrict__ kvp) {
  __shared__ float kt[32][33];
  __shared__ float vt[32][33];
  __shared__ float kmp[32][32];
  int bh = blockIdx.x, chunk = blockIdx.y;
  int b = bh >> 3, h = bh & 7;
  int t = threadIdx.x;
  float mx = smst[bh * 2 + 0], sc = smst[bh * 2 + 1];
  int lrow = t >> 3, lc4 = (t & 7) << 2;
  int d = t >> 3, e0 = (t & 7) << 2;
  float a0 = 0, a1 = 0, a2 = 0, a3 = 0;
  float km0 = 0, km1 = 0, km2 = 0, km3 = 0;
  int n_start = chunk << 9;                    // 512 per chunk
  for (int n0 = n_start; n0 < n_start + 512; n0 += 32) {
    int n = n0 + lrow;
    size_t g = (size_t)(b * N + n) * C4 + (h << 5) + lc4;
    float4 k4 = *reinterpret_cast<const float4*>(&qkvo[g + 256]);
    float4 v4 = *reinterpret_cast<const float4*>(&qkvo[g + 512]);
    float ef = expf(s[(size_t)bh * N + n] - mx) * sc;
    k4.x *= ef; k4.y *= ef; k4.z *= ef; k4.w *= ef;
    km0 += k4.x; km1 += k4.y; km2 += k4.z; km3 += k4.w;
    float2 cc = *reinterpret_cast<const float2*>(&cosT[(n << 4) + (lc4 >> 1)]);
    float2 ss = *reinterpret_cast<const float2*>(&sinT[(n << 4) + (lc4 >> 1)]);
    kt[lrow][lc4 + 0] = k4.x * cc.x - k4.y * ss.x;
    kt[lrow][lc4 + 1] = k4.x * ss.x + k4.y * cc.x;
    kt[lrow][lc4 + 2] = k4.z * cc.y - k4.w * ss.y;
    kt[lrow][lc4 + 3] = k4.z * ss.y + k4.w * cc.y;
    vt[lrow][lc4 + 0] = v4.x; vt[lrow][lc4 + 1] = v4.y;
    vt[lrow][lc4 + 2] = v4.z; vt[lrow][lc4 + 3] = v4.w;
    __syncthreads();
#pragma unroll
    for (int nn = 0; nn < 32; ++nn) {
      float kd = kt[nn][d];
      a0 = fmaf(kd, vt[nn][e0 + 0], a0);
      a1 = fmaf(kd, vt[nn][e0 + 1], a1);
      a2 = fmaf(kd, vt[nn][e0 + 2], a2);
      a3 = fmaf(kd, vt[nn][e0 + 3], a3);
    }
    __syncthreads();
  }
  size_t o = (size_t)(bh * 8 + chunk) * 1056;
  kvp[o + (d << 5) + e0 + 0] = a0;
  kvp[o + (d << 5) + e0 + 1] = a1;
  kvp[o + (d << 5) + e0 + 2] = a2;
  kvp[o + (d << 5) + e0 + 3] = a3;
  kmp[lrow][lc4 + 0] = km0; kmp[lrow][lc4 + 1] = km1;
  kmp[lrow][lc4 + 2] = km2; kmp[lrow][lc4 + 3] = km3;
  __syncthreads();
  if (t < 32) {
    float ssum = 0.f;
#pragma unroll
    for (int rr = 0; rr < 32; ++rr) ssum += kmp[rr][t];
    kvp[o + 1024 + t] = ssum;
  }
}

// ---- reduce 8 chunk partials -> kvkm[bh][1056], fold 1/N -------------------
__global__ void k_kvkm_reduce(const float* __restrict__ kvp,
                              float* __restrict__ kvkm) {
  int bh = blockIdx.x;
  int t = threadIdx.x;
  for (int j = t; j < 1056; j += 256) {
    float ssum = 0.f;
#pragma unroll
    for (int c = 0; c < 8; ++c) ssum += kvp[(size_t)(bh * 8 + c) * 1056 + j];
    kvkm[(size_t)bh * 1056 + j] = ssum * (1.0f / N);
  }
}

// -------- depthwise 5x5 conv on v (LEPE) -> staged into d_out rows ----------
__global__ __launch_bounds__(256) void k_lepe(
    const float* __restrict__ qkvo, const float* __restrict__ wgt,
    const float* __restrict__ lb, float* __restrict__ lepe_out, int b0) {
  int blk = blockIdx.x;                        // bpp*64*4
  int b = blk >> 8, rem = blk & 255;
  int y = rem >> 2, x0 = (rem & 3) << 4;       // 16 pixels along x
  int c = threadIdx.x;
  float w[25];
#pragma unroll
  for (int i = 0; i < 25; ++i) w[i] = wgt[c * 25 + i];
  float bias = lb[c];
  float acc[16];
#pragma unroll
  for (int p = 0; p < 16; ++p) acc[p] = bias;
#pragma unroll
  for (int dy = 0; dy < 5; ++dy) {
    int yy = y + dy - 2;
    if (yy < 0 || yy >= IH) continue;
    size_t rowb = (size_t)(b * N + (yy << 6)) * C4 + 512 + c;
#pragma unroll
    for (int dx = 0; dx < 5; ++dx) {
      float wv = w[dy * 5 + dx];
#pragma unroll
      for (int p = 0; p < 16; ++p) {
        int xx = x0 + p + dx - 2;
        if (xx < 0 || xx >= IW) continue;
        acc[p] = fmaf(qkvo[rowb + (size_t)xx * C4], wv, acc[p]);
      }
    }
  }
#pragma unroll
  for (int p = 0; p < 16; ++p)
    lepe_out[(size_t)((b0 + b) * N + (y << 6) + x0 + p) * C + c] = acc[p];
}

// -- opre = ((rope(q) @ kv) * z + lepe) * o, z = 1/(q.kmean+eps), in place ---
__global__ __launch_bounds__(256) void k_out_combine(
    float* __restrict__ qkvo, const float* __restrict__ kvkm,
    const float* __restrict__ cosT, const float* __restrict__ sinT,
    const float* __restrict__ lepe, int b0) {
  __shared__ float kvs[1024];
  __shared__ float kms[32];
  int bh = blockIdx.x, chunk = blockIdx.y;
  int b = bh >> 3, h = bh & 7;
  int t = threadIdx.x;
  reinterpret_cast<float4*>(kvs)[t] =
      reinterpret_cast<const float4*>(&kvkm[(size_t)bh * 1056])[t];
  if (t < 32) kms[t] = kvkm[(size_t)bh * 1056 + 1024 + t];
  __syncthreads();
  int n = (chunk << 8) + t;
  size_t rowbase = (size_t)(b * N + n) * C4;
  float q[32];
#pragma unroll
  for (int i = 0; i < 8; ++i) {
    float4 q4 = *reinterpret_cast<const float4*>(&qkvo[rowbase + (h << 5) + (i << 2)]);
    q[i * 4 + 0] = q4.x; q[i * 4 + 1] = q4.y; q[i * 4 + 2] = q4.z; q[i * 4 + 3] = q4.w;
  }
  float dot = 0.f;
#pragma unroll
  for (int dd = 0; dd < 32; ++dd) dot += q[dd] * kms[dd];
  float zv = 1.0f / (dot + 1e-6f);
  const float* cp = &cosT[n << 4];
  const float* sp = &sinT[n << 4];
#pragma unroll
  for (int j = 0; j < 16; ++j) {
    float cc = cp[j], ss = sp[j];
    float qr = q[2 * j], qi = q[2 * j + 1];
    q[2 * j]     = qr * cc - qi * ss;
    q[2 * j + 1] = qr * ss + qi * cc;
  }
  size_t oc = (size_t)((b0 + b) * N + n) * C + (h << 5);   // lepe rows in d_out
#pragma unroll
  for (int e4 = 0; e4 < 8; ++e4) {
    float ax = 0, ay = 0, az = 0, aw = 0;
#pragma unroll
    for (int dd = 0; dd < 32; ++dd) {
      float4 kv4 = *reinterpret_cast<const float4*>(&kvs[(dd << 5) + (e4 << 2)]);
      float qd = q[dd];
      ax = fmaf(qd, kv4.x, ax); ay = fmaf(qd, kv4.y, ay);
      az = fmaf(qd, kv4.z, az); aw = fmaf(qd, kv4.w, aw);
    }
    float4 lp = *reinterpret_cast<const float4*>(&lepe[oc + (e4 << 2)]);
    float4 ov = *reinterpret_cast<const float4*>(
        &qkvo[rowbase + 768 + (h << 5) + (e4 << 2)]);
    float4 r;
    r.x = (ax * zv + lp.x) * ov.x;
    r.y = (ay * zv + lp.y) * ov.y;
    r.z = (az * zv + lp.z) * ov.z;
    r.w = (aw * zv + lp.w) * ov.w;
    *reinterpret_cast<float4*>(&qkvo[rowbase + (h << 5) + (e4 << 2)]) = r;
  }
}

// ---------------------------------------------------------------------------
static inline size_t ws_bytes_needed(int bpp) {
  size_t pn = (size_t)bpp * N;
  size_t f32c = pn * C4                       // qkvo
              + (size_t)bpp * 32 * 256        // qmean partials
              + (size_t)bpp * NH * 32         // qmean
              + (size_t)bpp * NH * 2          // smstats
              + (size_t)bpp * NH * N          // scores
              + (size_t)bpp * NH * 8 * 1056   // kv+km partials
              + (size_t)bpp * NH * 1056       // kvkm
              + (size_t)N * 16 * 2;           // cos/sin
  size_t f16c = (size_t)C * C4 * 2            // wq T splits
              + (size_t)C * C * 2;            // wp T splits
  return f32c * 4 + f16c * 2;
}

extern "C" void kernel_launch(void* const* d_in, const int* in_sizes, int n_in,
                              void* d_out, int out_size, void* d_ws, size_t ws_size,
                              hipStream_t stream) {
  const float* x      = (const float*)d_in[0];
  const float* w_qkvo = (const float*)d_in[1];
  const float* b_qkvo = (const float*)d_in[2];
  const float* lepe_w = (const float*)d_in[3];
  const float* lepe_b = (const float*)d_in[4];
  const float* w_proj = (const float*)d_in[5];
  const float* b_proj = (const float*)d_in[6];
  float* out = (float*)d_out;
  float* ws  = (float*)d_ws;

  int bpp = 2;
  if (ws_bytes_needed(16) <= ws_size) bpp = 16;
  else if (ws_bytes_needed(8) <= ws_size) bpp = 8;
  else if (ws_bytes_needed(4) <= ws_size) bpp = 4;

  size_t pn = (size_t)bpp * N;
  int nbh = bpp * NH;
  float* qkvo  = ws;
  float* qpart = qkvo  + pn * C4;
  float* qmean = qpart + (size_t)bpp * 32 * 256;
  float* smst  = qmean + (size_t)nbh * 32;
  float* sbuf  = smst  + (size_t)nbh * 2;
  float* kvp   = sbuf  + (size_t)nbh * N;
  float* kvkm  = kvp   + (size_t)nbh * 8 * 1056;
  float* cosT  = kvkm  + (size_t)nbh * 1056;
  float* sinT  = cosT  + (size_t)N * 16;
  _Float16* wqh = (_Float16*)(sinT + (size_t)N * 16);
  _Float16* wql = wqh + (size_t)C * C4;
  _Float16* wph = wql + (size_t)C * C4;
  _Float16* wpl = wph + (size_t)C * C;

  k_tables<<<N * 16 / 256, 256, 0, stream>>>(cosT, sinT);
  k_split_wT<<<C4, 256, 0, stream>>>(w_qkvo, C4, wqh, wql);
  k_split_wT<<<C, 256, 0, stream>>>(w_proj, C, wph, wpl);

  for (int b0 = 0; b0 < B; b0 += bpp) {
    // GEMM1: qkvo = x@w_qkvo + b, elu on cols<512, qmean partials fused
    k_gemm_split<<<dim3(pn / 128, C4 / 128), 256, 0, stream>>>(
        x + (size_t)b0 * N * C, C, wqh, wql, b_qkvo, qkvo, C4, 512, qpart);
    k_qmean_fin<<<(nbh * 32 + 255) / 256, 256, 0, stream>>>(qpart, qmean, nbh * 32);
    k_scores<<<(nbh * N) / 256, 256, 0, stream>>>(qkvo, qmean, sbuf);
    k_smstats<<<nbh, 256, 0, stream>>>(sbuf, smst);
    k_kvkm_partial<<<dim3(nbh, 8), 256, 0, stream>>>(qkvo, sbuf, smst, cosT, sinT, kvp);
    k_kvkm_reduce<<<nbh, 256, 0, stream>>>(kvp, kvkm);
    k_lepe<<<bpp * IH * 4, 256, 0, stream>>>(qkvo, lepe_w, lepe_b, out, b0);
    k_out_combine<<<dim3(nbh, 16), 256, 0, stream>>>(qkvo, kvkm, cosT, sinT, out, b0);
    // GEMM2: out = opre @ w_proj + b (A = f32 opre in qkvo q-slot)
    k_gemm_split<<<dim3(pn / 128, C / 128), 256, 0, stream>>>(
        qkvo, C4, wph, wpl, b_proj, out + (size_t)b0 * N * C, C, 0, nullptr);
  }
}

// Round 12
// 568.552 us; speedup vs baseline: 2.2804x; 1.0142x over previous
//
#include <hip/hip_runtime.h>
#include <math.h>

// RALALinearAttention on MI355X — round 12.
// r11 = 576us (best). Remaining: ~335us in small kernels vs ~106us ideal BW.
// r12: flash-style fusion of the stats chain at FULL occupancy:
//  - k_kvflash (nbh x 8 blocks): qmean(from qpart) -> chunk scores (LDS) ->
//    chunk-local max/sum -> kv/km partials weighted exp(s - mx_c).
//  - k_kvfinal: exact log-sum-exp merge of the 8 chunks.
//  Deletes k_qmean_fin / k_scores / k_smstats and the 16MB scores buffer.
// GEMMs unchanged from r11 (91us / 23us, qmean partials fused in GEMM1).
constexpr int B   = 16;
constexpr int IH  = 64;
constexpr int IW  = 64;
constexpr int C   = 256;
constexpr int NH  = 8;
constexpr int HD  = 32;
constexpr int N   = IH * IW;    // 4096
constexpr int C4  = 4 * C;      // 1024

using f16x8 = __attribute__((ext_vector_type(8))) _Float16;
using f32x4 = __attribute__((ext_vector_type(4))) float;

// ---------------------------------------------------------------- tables ----
__global__ void k_tables(float* __restrict__ cosT, float* __restrict__ sinT) {
  int t = blockIdx.x * 256 + threadIdx.x;      // N*16 = 65536
  int j = t & 15, pix = t >> 4;
  int y = pix >> 6, x = pix & 63;
  int jj = j & 7;
  double theta = pow(10000.0, -(double)jj / 8.0);
  double pos = (j < 8) ? (double)y : (double)x;
  double ang = pos * theta;
  cosT[t] = (float)cos(ang);
  sinT[t] = (float)sin(ang);
}

// ------------- split weight [K=256][ldb] -> transposed [ldb][256] -----------
__global__ void k_split_wT(const float* __restrict__ w, int ldb,
                           _Float16* __restrict__ hiT, _Float16* __restrict__ loT) {
  int n = blockIdx.x;           // column of w
  int k = threadIdx.x;          // 0..255
  float v = w[(size_t)k * ldb + n];
  _Float16 h = (_Float16)v;
  hiT[(size_t)n * 256 + k] = h;
  loT[(size_t)n * 256 + k] = (_Float16)(v - (float)h);
}

// --------------- split-f16 MFMA GEMM (r7 structure) + qmean partials --------
__global__ __launch_bounds__(256) void k_gemm_split(
    const float* __restrict__ A, int lda,
    const _Float16* __restrict__ BhT, const _Float16* __restrict__ BlT,
    const float* __restrict__ bias, float* __restrict__ Cm, int ldc,
    int nelu, float* __restrict__ qpart) {
  __shared__ _Float16 lds[4 * 5120];          // Ah | Al | Bh | Bl, stride 40
  _Float16* AhL = lds;
  _Float16* AlL = lds + 5120;
  _Float16* BhL = lds + 10240;
  _Float16* BlL = lds + 15360;
  int t = threadIdx.x;
  int m0 = blockIdx.x * 128, n0 = blockIdx.y * 128;
  int lane = t & 63;
  int wm = t >> 7, wn = (t >> 6) & 1;
  int lr = lane & 15, lg = lane >> 4;
  int srow = t >> 1, sseg = t & 1;            // one row-half per thread

  f32x4 acc[4][4] = {};

  const float* aP = &A[(size_t)(m0 + srow) * lda + sseg * 16];
  const _Float16* bhP = &BhT[(size_t)(n0 + srow) * 256 + sseg * 16];
  const _Float16* blP = &BlT[(size_t)(n0 + srow) * 256 + sseg * 16];
  float4 ar0 = *(const float4*)(aP + 0);
  float4 ar1 = *(const float4*)(aP + 4);
  float4 ar2 = *(const float4*)(aP + 8);
  float4 ar3 = *(const float4*)(aP + 12);
  f16x8 brh0 = *(const f16x8*)(bhP + 0);
  f16x8 brh1 = *(const f16x8*)(bhP + 8);
  f16x8 brl0 = *(const f16x8*)(blP + 0);
  f16x8 brl1 = *(const f16x8*)(blP + 8);

  for (int kc = 0; kc < 256; kc += 32) {
    {
      float av[16] = {ar0.x, ar0.y, ar0.z, ar0.w, ar1.x, ar1.y, ar1.z, ar1.w,
                      ar2.x, ar2.y, ar2.z, ar2.w, ar3.x, ar3.y, ar3.z, ar3.w};
      f16x8 h0, h1, l0, l1;
#pragma unroll
      for (int j = 0; j < 8; ++j) {
        _Float16 h = (_Float16)av[j];
        h0[j] = h; l0[j] = (_Float16)(av[j] - (float)h);
        _Float16 h2 = (_Float16)av[j + 8];
        h1[j] = h2; l1[j] = (_Float16)(av[j + 8] - (float)h2);
      }
      int d = srow * 40 + sseg * 16;
      *(f16x8*)&AhL[d] = h0; *(f16x8*)&AhL[d + 8] = h1;
      *(f16x8*)&AlL[d] = l0; *(f16x8*)&AlL[d + 8] = l1;
      *(f16x8*)&BhL[d] = brh0; *(f16x8*)&BhL[d + 8] = brh1;
      *(f16x8*)&BlL[d] = brl0; *(f16x8*)&BlL[d + 8] = brl1;
    }
    __syncthreads();

    if (kc + 32 < 256) {
      const float* aN = aP + kc + 32;
      const _Float16* bhN = bhP + kc + 32;
      const _Float16* blN = blP + kc + 32;
      ar0 = *(const float4*)(aN + 0);
      ar1 = *(const float4*)(aN + 4);
      ar2 = *(const float4*)(aN + 8);
      ar3 = *(const float4*)(aN + 12);
      brh0 = *(const f16x8*)(bhN + 0);
      brh1 = *(const f16x8*)(bhN + 8);
      brl0 = *(const f16x8*)(blN + 0);
      brl1 = *(const f16x8*)(blN + 8);
    }

    f16x8 ah[4], al[4];
#pragma unroll
    for (int mi = 0; mi < 4; ++mi) {
      int ar = (wm * 64 + mi * 16 + lr) * 40 + lg * 8;
      ah[mi] = *(const f16x8*)&AhL[ar];
      al[mi] = *(const f16x8*)&AlL[ar];
    }
#pragma unroll
    for (int ni = 0; ni < 4; ++ni) {
      int br = (wn * 64 + ni * 16 + lr) * 40 + lg * 8;
      f16x8 bh = *(const f16x8*)&BhL[br];
      f16x8 bl = *(const f16x8*)&BlL[br];
#pragma unroll
      for (int mi = 0; mi < 4; ++mi) {
        acc[mi][ni] = __builtin_amdgcn_mfma_f32_16x16x32_f16(ah[mi], bh, acc[mi][ni], 0, 0, 0);
        acc[mi][ni] = __builtin_amdgcn_mfma_f32_16x16x32_f16(al[mi], bh, acc[mi][ni], 0, 0, 0);
        acc[mi][ni] = __builtin_amdgcn_mfma_f32_16x16x32_f16(ah[mi], bl, acc[mi][ni], 0, 0, 0);
      }
    }
    __syncthreads();
  }

  // ---- epilogue: LDS transpose -> coalesced float4 stores (+ qmean qs) ----
  float* Cl = reinterpret_cast<float*>(lds);   // 32 x 132 f32
  int ri2 = t >> 3, c0 = (t & 7) << 4;
  bool doq = (qpart != nullptr) && (n0 < 256);  // block-uniform
  float qs[16] = {};
#pragma unroll
  for (int mi = 0; mi < 4; ++mi) {
#pragma unroll
    for (int ni = 0; ni < 4; ++ni) {
      int col = wn * 64 + ni * 16 + lr;
#pragma unroll
      for (int r = 0; r < 4; ++r)
        Cl[(wm * 16 + lg * 4 + r) * 132 + col] = acc[mi][ni][r];
    }
    __syncthreads();
    int grow = m0 + (ri2 >> 4) * 64 + mi * 16 + (ri2 & 15);
#pragma unroll
    for (int j = 0; j < 4; ++j) {
      int col = n0 + c0 + j * 4;
      float4 v = *(const float4*)&Cl[ri2 * 132 + c0 + j * 4];
      float4 bb = *(const float4*)&bias[col];
      v.x += bb.x; v.y += bb.y; v.z += bb.z; v.w += bb.w;
      if (col < nelu) {
        v.x = (v.x > 0.f) ? v.x + 1.f : expf(v.x);
        v.y = (v.y > 0.f) ? v.y + 1.f : expf(v.y);
        v.z = (v.z > 0.f) ? v.z + 1.f : expf(v.z);
        v.w = (v.w > 0.f) ? v.w + 1.f : expf(v.w);
      }
      if (doq) {
        qs[j * 4 + 0] += v.x; qs[j * 4 + 1] += v.y;
        qs[j * 4 + 2] += v.z; qs[j * 4 + 3] += v.w;
      }
      *(float4*)&Cm[(size_t)grow * ldc + col] = v;
    }
    __syncthreads();
  }
  if (doq) {
#pragma unroll
    for (int j = 0; j < 4; ++j) {
      float4 w4 = {qs[j*4+0], qs[j*4+1], qs[j*4+2], qs[j*4+3]};
      *(float4*)&Cl[ri2 * 132 + c0 + j * 4] = w4;
    }
    __syncthreads();
    if (t < 128) {
      float ssum = 0.f;
#pragma unroll
      for (int rr = 0; rr < 32; ++rr) ssum += Cl[rr * 132 + t];
      int b_local = m0 >> 12, rowblk = (m0 >> 7) & 31;
      qpart[(size_t)(b_local * 32 + rowblk) * 256 + n0 + t] = ssum;
    }
  }
}

// ---- flash kv: qmean -> chunk scores -> local softmax -> kv/km partials ----
// grid (nbh, 8); chunk = 512 n. kvp layout per (bh,chunk): 1024 kv + 32 km +
// mx_c + sum_c  (stride 1058).
__global__ __launch_bounds__(256) void k_kvflash(
    const float* __restrict__ qkvo, const float* __restrict__ qpart,
    const float* __restrict__ cosT, const float* __restrict__ sinT,
    float* __restrict__ kvp) {
  __shared__ float qm[32];
  __shared__ float sL[512];
  __shared__ float red[256];
  __shared__ float kt[32][33];
  __shared__ float vt[32][33];
  __shared__ float kmp[32][32];
  int bh = blockIdx.x, chunk = blockIdx.y;
  int b = bh >> 3, h = bh & 7;
  int t = threadIdx.x;
  int nbase = chunk << 9;

  // phase 0: qmean from GEMM1 partials (fold 1/N and softmax scale)
  if (t < 32) {
    float s = 0.f;
#pragma unroll
    for (int rb = 0; rb < 32; ++rb)
      s += qpart[(size_t)(b * 32 + rb) * 256 + (h << 5) + t];
    qm[t] = s * (1.0f / N) * 0.1767766952966369f;
  }
  __syncthreads();

  // phase A: scores for this chunk's 512 n; chunk max and exp-sum
  float qmr[32];
#pragma unroll
  for (int i = 0; i < 32; ++i) qmr[i] = qm[i];
  float mx = -3.4e38f;
#pragma unroll
  for (int i = 0; i < 2; ++i) {
    int n = nbase + t + i * 256;
    const float* kp = &qkvo[(size_t)(b * N + n) * C4 + 256 + (h << 5)];
    float dot = 0.f;
#pragma unroll
    for (int j = 0; j < 8; ++j) {
      float4 k4 = *(const float4*)(kp + (j << 2));
      dot += k4.x * qmr[j*4] + k4.y * qmr[j*4+1] + k4.z * qmr[j*4+2] + k4.w * qmr[j*4+3];
    }
    sL[t + i * 256] = dot;
    mx = fmaxf(mx, dot);
  }
  red[t] = mx; __syncthreads();
  for (int off = 128; off > 0; off >>= 1) {
    if (t < off) red[t] = fmaxf(red[t], red[t + off]);
    __syncthreads();
  }
  float mx_c = red[0];
  __syncthreads();
  float psum = expf(sL[t] - mx_c) + expf(sL[t + 256] - mx_c);
  red[t] = psum; __syncthreads();
  for (int off = 128; off > 0; off >>= 1) {
    if (t < off) red[t] += red[t + off];
    __syncthreads();
  }
  float sum_c = red[0];

  // phase B: kv/km partials with ef = exp(s - mx_c), rope(k) fused
  int lrow = t >> 3, lc4 = (t & 7) << 2;
  int d = t >> 3, e0 = (t & 7) << 2;
  float a0 = 0, a1 = 0, a2 = 0, a3 = 0;
  float km0 = 0, km1 = 0, km2 = 0, km3 = 0;
  for (int n0 = nbase; n0 < nbase + 512; n0 += 32) {
    int n = n0 + lrow;
    size_t g = (size_t)(b * N + n) * C4 + (h << 5) + lc4;
    float4 k4 = *reinterpret_cast<const float4*>(&qkvo[g + 256]);
    float4 v4 = *reinterpret_cast<const float4*>(&qkvo[g + 512]);
    float ef = expf(sL[n - nbase] - mx_c);
    k4.x *= ef; k4.y *= ef; k4.z *= ef; k4.w *= ef;
    km0 += k4.x; km1 += k4.y; km2 += k4.z; km3 += k4.w;
    float2 cc = *reinterpret_cast<const float2*>(&cosT[(n << 4) + (lc4 >> 1)]);
    float2 ss = *reinterpret_cast<const float2*>(&sinT[(n << 4) + (lc4 >> 1)]);
    kt[lrow][lc4 + 0] = k4.x * cc.x - k4.y * ss.x;
    kt[lrow][lc4 + 1] = k4.x * ss.x + k4.y * cc.x;
    kt[lrow][lc4 + 2] = k4.z * cc.y - k4.w * ss.y;
    kt[lrow][lc4 + 3] = k4.z * ss.y + k4.w * cc.y;
    vt[lrow][lc4 + 0] = v4.x; vt[lrow][lc4 + 1] = v4.y;
    vt[lrow][lc4 + 2] = v4.z; vt[lrow][lc4 + 3] = v4.w;
    __syncthreads();
#pragma unroll
    for (int nn = 0; nn < 32; ++nn) {
      float kd = kt[nn][d];
      a0 = fmaf(kd, vt[nn][e0 + 0], a0);
      a1 = fmaf(kd, vt[nn][e0 + 1], a1);
      a2 = fmaf(kd, vt[nn][e0 + 2], a2);
      a3 = fmaf(kd, vt[nn][e0 + 3], a3);
    }
    __syncthreads();
  }
  size_t o = (size_t)(bh * 8 + chunk) * 1058;
  kvp[o + (d << 5) + e0 + 0] = a0;
  kvp[o + (d << 5) + e0 + 1] = a1;
  kvp[o + (d << 5) + e0 + 2] = a2;
  kvp[o + (d << 5) + e0 + 3] = a3;
  kmp[lrow][lc4 + 0] = km0; kmp[lrow][lc4 + 1] = km1;
  kmp[lrow][lc4 + 2] = km2; kmp[lrow][lc4 + 3] = km3;
  __syncthreads();
  if (t < 32) {
    float ssum = 0.f;
#pragma unroll
    for (int rr = 0; rr < 32; ++rr) ssum += kmp[rr][t];
    kvp[o + 1024 + t] = ssum;
  }
  if (t == 0) {
    kvp[o + 1056] = mx_c;
    kvp[o + 1057] = sum_c;
  }
}

// ---- exact log-sum-exp merge of 8 chunks -> kvkm[bh][1056] -----------------
__global__ __launch_bounds__(256) void k_kvfinal(
    const float* __restrict__ kvp, float* __restrict__ kvkm) {
  __shared__ float fc[8];
  int bh = blockIdx.x;
  int t = threadIdx.x;
  if (t == 0) {
    float mxs[8], sums[8];
    float mx = -3.4e38f;
#pragma unroll
    for (int c = 0; c < 8; ++c) {
      size_t o = (size_t)(bh * 8 + c) * 1058;
      mxs[c] = kvp[o + 1056];
      sums[c] = kvp[o + 1057];
      mx = fmaxf(mx, mxs[c]);
    }
    float T = 0.f;
#pragma unroll
    for (int c = 0; c < 8; ++c) T += sums[c] * expf(mxs[c] - mx);
    float invT = 1.0f / T;
#pragma unroll
    for (int c = 0; c < 8; ++c) fc[c] = expf(mxs[c] - mx) * invT;
  }
  __syncthreads();
  float f0 = fc[0], f1 = fc[1], f2 = fc[2], f3 = fc[3];
  float f4 = fc[4], f5 = fc[5], f6 = fc[6], f7 = fc[7];
  for (int j = t; j < 1056; j += 256) {
    size_t o = (size_t)(bh * 8) * 1058 + j;
    float v = kvp[o] * f0 + kvp[o + 1058] * f1 + kvp[o + 2 * 1058] * f2 +
              kvp[o + 3 * 1058] * f3 + kvp[o + 4 * 1058] * f4 +
              kvp[o + 5 * 1058] * f5 + kvp[o + 6 * 1058] * f6 +
              kvp[o + 7 * 1058] * f7;
    kvkm[(size_t)bh * 1056 + j] = v;
  }
}

// -------- depthwise 5x5 conv on v (LEPE) -> staged into d_out rows ----------
__global__ __launch_bounds__(256) void k_lepe(
    const float* __restrict__ qkvo, const float* __restrict__ wgt,
    const float* __restrict__ lb, float* __restrict__ lepe_out, int b0) {
  int blk = blockIdx.x;                        // bpp*64*4
  int b = blk >> 8, rem = blk & 255;
  int y = rem >> 2, x0 = (rem & 3) << 4;       // 16 pixels along x
  int c = threadIdx.x;
  float w[25];
#pragma unroll
  for (int i = 0; i < 25; ++i) w[i] = wgt[c * 25 + i];
  float bias = lb[c];
  float acc[16];
#pragma unroll
  for (int p = 0; p < 16; ++p) acc[p] = bias;
#pragma unroll
  for (int dy = 0; dy < 5; ++dy) {
    int yy = y + dy - 2;
    if (yy < 0 || yy >= IH) continue;
    size_t rowb = (size_t)(b * N + (yy << 6)) * C4 + 512 + c;
#pragma unroll
    for (int dx = 0; dx < 5; ++dx) {
      float wv = w[dy * 5 + dx];
#pragma unroll
      for (int p = 0; p < 16; ++p) {
        int xx = x0 + p + dx - 2;
        if (xx < 0 || xx >= IW) continue;
        acc[p] = fmaf(qkvo[rowb + (size_t)xx * C4], wv, acc[p]);
      }
    }
  }
#pragma unroll
  for (int p = 0; p < 16; ++p)
    lepe_out[(size_t)((b0 + b) * N + (y << 6) + x0 + p) * C + c] = acc[p];
}

// -- opre = ((rope(q) @ kv) * z + lepe) * o, z = 1/(q.kmean+eps), in place ---
__global__ __launch_bounds__(256) void k_out_combine(
    float* __restrict__ qkvo, const float* __restrict__ kvkm,
    const float* __restrict__ cosT, const float* __restrict__ sinT,
    const float* __restrict__ lepe, int b0) {
  __shared__ float kvs[1024];
  __shared__ float kms[32];
  int bh = blockIdx.x, chunk = blockIdx.y;
  int b = bh >> 3, h = bh & 7;
  int t = threadIdx.x;
  reinterpret_cast<float4*>(kvs)[t] =
      reinterpret_cast<const float4*>(&kvkm[(size_t)bh * 1056])[t];
  if (t < 32) kms[t] = kvkm[(size_t)bh * 1056 + 1024 + t];
  __syncthreads();
  int n = (chunk << 8) + t;
  size_t rowbase = (size_t)(b * N + n) * C4;
  float q[32];
#pragma unroll
  for (int i = 0; i < 8; ++i) {
    float4 q4 = *reinterpret_cast<const float4*>(&qkvo[rowbase + (h << 5) + (i << 2)]);
    q[i * 4 + 0] = q4.x; q[i * 4 + 1] = q4.y; q[i * 4 + 2] = q4.z; q[i * 4 + 3] = q4.w;
  }
  float dot = 0.f;
#pragma unroll
  for (int dd = 0; dd < 32; ++dd) dot += q[dd] * kms[dd];
  float zv = 1.0f / (dot + 1e-6f);
  const float* cp = &cosT[n << 4];
  const float* sp = &sinT[n << 4];
#pragma unroll
  for (int j = 0; j < 16; ++j) {
    float cc = cp[j], ss = sp[j];
    float qr = q[2 * j], qi = q[2 * j + 1];
    q[2 * j]     = qr * cc - qi * ss;
    q[2 * j + 1] = qr * ss + qi * cc;
  }
  size_t oc = (size_t)((b0 + b) * N + n) * C + (h << 5);   // lepe rows in d_out
#pragma unroll
  for (int e4 = 0; e4 < 8; ++e4) {
    float ax = 0, ay = 0, az = 0, aw = 0;
#pragma unroll
    for (int dd = 0; dd < 32; ++dd) {
      float4 kv4 = *reinterpret_cast<const float4*>(&kvs[(dd << 5) + (e4 << 2)]);
      float qd = q[dd];
      ax = fmaf(qd, kv4.x, ax); ay = fmaf(qd, kv4.y, ay);
      az = fmaf(qd, kv4.z, az); aw = fmaf(qd, kv4.w, aw);
    }
    float4 lp = *reinterpret_cast<const float4*>(&lepe[oc + (e4 << 2)]);
    float4 ov = *reinterpret_cast<const float4*>(
        &qkvo[rowbase + 768 + (h << 5) + (e4 << 2)]);
    float4 r;
    r.x = (ax * zv + lp.x) * ov.x;
    r.y = (ay * zv + lp.y) * ov.y;
    r.z = (az * zv + lp.z) * ov.z;
    r.w = (aw * zv + lp.w) * ov.w;
    *reinterpret_cast<float4*>(&qkvo[rowbase + (h << 5) + (e4 << 2)]) = r;
  }
}

// ---------------------------------------------------------------------------
static inline size_t ws_bytes_needed(int bpp) {
  size_t pn = (size_t)bpp * N;
  size_t f32c = pn * C4                       // qkvo
              + (size_t)bpp * 32 * 256        // qmean partials
              + (size_t)bpp * NH * 8 * 1058   // kv+km+stats partials
              + (size_t)bpp * NH * 1056       // kvkm
              + (size_t)N * 16 * 2;           // cos/sin
  size_t f16c = (size_t)C * C4 * 2            // wq T splits
              + (size_t)C * C * 2;            // wp T splits
  return f32c * 4 + f16c * 2;
}

extern "C" void kernel_launch(void* const* d_in, const int* in_sizes, int n_in,
                              void* d_out, int out_size, void* d_ws, size_t ws_size,
                              hipStream_t stream) {
  const float* x      = (const float*)d_in[0];
  const float* w_qkvo = (const float*)d_in[1];
  const float* b_qkvo = (const float*)d_in[2];
  const float* lepe_w = (const float*)d_in[3];
  const float* lepe_b = (const float*)d_in[4];
  const float* w_proj = (const float*)d_in[5];
  const float* b_proj = (const float*)d_in[6];
  float* out = (float*)d_out;
  float* ws  = (float*)d_ws;

  int bpp = 2;
  if (ws_bytes_needed(16) <= ws_size) bpp = 16;
  else if (ws_bytes_needed(8) <= ws_size) bpp = 8;
  else if (ws_bytes_needed(4) <= ws_size) bpp = 4;

  size_t pn = (size_t)bpp * N;
  int nbh = bpp * NH;
  float* qkvo  = ws;
  float* qpart = qkvo  + pn * C4;
  float* kvp   = qpart + (size_t)bpp * 32 * 256;
  float* kvkm  = kvp   + (size_t)nbh * 8 * 1058;
  float* cosT  = kvkm  + (size_t)nbh * 1056;
  float* sinT  = cosT  + (size_t)N * 16;
  _Float16* wqh = (_Float16*)(sinT + (size_t)N * 16);
  _Float16* wql = wqh + (size_t)C * C4;
  _Float16* wph = wql + (size_t)C * C4;
  _Float16* wpl = wph + (size_t)C * C;

  k_tables<<<N * 16 / 256, 256, 0, stream>>>(cosT, sinT);
  k_split_wT<<<C4, 256, 0, stream>>>(w_qkvo, C4, wqh, wql);
  k_split_wT<<<C, 256, 0, stream>>>(w_proj, C, wph, wpl);

  for (int b0 = 0; b0 < B; b0 += bpp) {
    // GEMM1: qkvo = x@w_qkvo + b, elu on cols<512, qmean partials fused
    k_gemm_split<<<dim3(pn / 128, C4 / 128), 256, 0, stream>>>(
        x + (size_t)b0 * N * C, C, wqh, wql, b_qkvo, qkvo, C4, 512, qpart);
    k_kvflash<<<dim3(nbh, 8), 256, 0, stream>>>(qkvo, qpart, cosT, sinT, kvp);
    k_kvfinal<<<nbh, 256, 0, stream>>>(kvp, kvkm);
    k_lepe<<<bpp * IH * 4, 256, 0, stream>>>(qkvo, lepe_w, lepe_b, out, b0);
    k_out_combine<<<dim3(nbh, 16), 256, 0, stream>>>(qkvo, kvkm, cosT, sinT, out, b0);
    // GEMM2: out = opre @ w_proj + b (A = f32 opre in qkvo q-slot)
    k_gemm_split<<<dim3(pn / 128, C / 128), 256, 0, stream>>>(
        qkvo, C4, wph, wpl, b_proj, out + (size_t)b0 * N * C, C, 0, nullptr);
  }
}

// Round 13
// 539.791 us; speedup vs baseline: 2.4019x; 1.0533x over previous
//
#include <hip/hip_runtime.h>
#include <math.h>

// RALALinearAttention on MI355X — round 13.
// r12 = 568us. ~330us still in small kernels; k_kvflash phase B was
// LDS-instruction-bound (5 scalar ds_read per 4 FMA).
// r13: register-tiled kv (4dx4e per thread, 2x ds_read_b128 per 16 FMA,
// 4 lane-groups x 128-row subchunks, LDS merge), km in regs during staging.
// GEMMs unchanged (proven 92/23us).
constexpr int B   = 16;
constexpr int IH  = 64;
constexpr int IW  = 64;
constexpr int C   = 256;
constexpr int NH  = 8;
constexpr int HD  = 32;
constexpr int N   = IH * IW;    // 4096
constexpr int C4  = 4 * C;      // 1024

using f16x8 = __attribute__((ext_vector_type(8))) _Float16;
using f32x4 = __attribute__((ext_vector_type(4))) float;

// ---------------------------------------------------------------- tables ----
__global__ void k_tables(float* __restrict__ cosT, float* __restrict__ sinT) {
  int t = blockIdx.x * 256 + threadIdx.x;      // N*16 = 65536
  int j = t & 15, pix = t >> 4;
  int y = pix >> 6, x = pix & 63;
  int jj = j & 7;
  double theta = pow(10000.0, -(double)jj / 8.0);
  double pos = (j < 8) ? (double)y : (double)x;
  double ang = pos * theta;
  cosT[t] = (float)cos(ang);
  sinT[t] = (float)sin(ang);
}

// ------------- split weight [K=256][ldb] -> transposed [ldb][256] -----------
__global__ void k_split_wT(const float* __restrict__ w, int ldb,
                           _Float16* __restrict__ hiT, _Float16* __restrict__ loT) {
  int n = blockIdx.x;           // column of w
  int k = threadIdx.x;          // 0..255
  float v = w[(size_t)k * ldb + n];
  _Float16 h = (_Float16)v;
  hiT[(size_t)n * 256 + k] = h;
  loT[(size_t)n * 256 + k] = (_Float16)(v - (float)h);
}

// --------------- split-f16 MFMA GEMM (r7 structure) + qmean partials --------
__global__ __launch_bounds__(256) void k_gemm_split(
    const float* __restrict__ A, int lda,
    const _Float16* __restrict__ BhT, const _Float16* __restrict__ BlT,
    const float* __restrict__ bias, float* __restrict__ Cm, int ldc,
    int nelu, float* __restrict__ qpart) {
  __shared__ _Float16 lds[4 * 5120];          // Ah | Al | Bh | Bl, stride 40
  _Float16* AhL = lds;
  _Float16* AlL = lds + 5120;
  _Float16* BhL = lds + 10240;
  _Float16* BlL = lds + 15360;
  int t = threadIdx.x;
  int m0 = blockIdx.x * 128, n0 = blockIdx.y * 128;
  int lane = t & 63;
  int wm = t >> 7, wn = (t >> 6) & 1;
  int lr = lane & 15, lg = lane >> 4;
  int srow = t >> 1, sseg = t & 1;            // one row-half per thread

  f32x4 acc[4][4] = {};

  const float* aP = &A[(size_t)(m0 + srow) * lda + sseg * 16];
  const _Float16* bhP = &BhT[(size_t)(n0 + srow) * 256 + sseg * 16];
  const _Float16* blP = &BlT[(size_t)(n0 + srow) * 256 + sseg * 16];
  float4 ar0 = *(const float4*)(aP + 0);
  float4 ar1 = *(const float4*)(aP + 4);
  float4 ar2 = *(const float4*)(aP + 8);
  float4 ar3 = *(const float4*)(aP + 12);
  f16x8 brh0 = *(const f16x8*)(bhP + 0);
  f16x8 brh1 = *(const f16x8*)(bhP + 8);
  f16x8 brl0 = *(const f16x8*)(blP + 0);
  f16x8 brl1 = *(const f16x8*)(blP + 8);

  for (int kc = 0; kc < 256; kc += 32) {
    {
      float av[16] = {ar0.x, ar0.y, ar0.z, ar0.w, ar1.x, ar1.y, ar1.z, ar1.w,
                      ar2.x, ar2.y, ar2.z, ar2.w, ar3.x, ar3.y, ar3.z, ar3.w};
      f16x8 h0, h1, l0, l1;
#pragma unroll
      for (int j = 0; j < 8; ++j) {
        _Float16 h = (_Float16)av[j];
        h0[j] = h; l0[j] = (_Float16)(av[j] - (float)h);
        _Float16 h2 = (_Float16)av[j + 8];
        h1[j] = h2; l1[j] = (_Float16)(av[j + 8] - (float)h2);
      }
      int d = srow * 40 + sseg * 16;
      *(f16x8*)&AhL[d] = h0; *(f16x8*)&AhL[d + 8] = h1;
      *(f16x8*)&AlL[d] = l0; *(f16x8*)&AlL[d + 8] = l1;
      *(f16x8*)&BhL[d] = brh0; *(f16x8*)&BhL[d + 8] = brh1;
      *(f16x8*)&BlL[d] = brl0; *(f16x8*)&BlL[d + 8] = brl1;
    }
    __syncthreads();

    if (kc + 32 < 256) {
      const float* aN = aP + kc + 32;
      const _Float16* bhN = bhP + kc + 32;
      const _Float16* blN = blP + kc + 32;
      ar0 = *(const float4*)(aN + 0);
      ar1 = *(const float4*)(aN + 4);
      ar2 = *(const float4*)(aN + 8);
      ar3 = *(const float4*)(aN + 12);
      brh0 = *(const f16x8*)(bhN + 0);
      brh1 = *(const f16x8*)(bhN + 8);
      brl0 = *(const f16x8*)(blN + 0);
      brl1 = *(const f16x8*)(blN + 8);
    }

    f16x8 ah[4], al[4];
#pragma unroll
    for (int mi = 0; mi < 4; ++mi) {
      int ar = (wm * 64 + mi * 16 + lr) * 40 + lg * 8;
      ah[mi] = *(const f16x8*)&AhL[ar];
      al[mi] = *(const f16x8*)&AlL[ar];
    }
#pragma unroll
    for (int ni = 0; ni < 4; ++ni) {
      int br = (wn * 64 + ni * 16 + lr) * 40 + lg * 8;
      f16x8 bh = *(const f16x8*)&BhL[br];
      f16x8 bl = *(const f16x8*)&BlL[br];
#pragma unroll
      for (int mi = 0; mi < 4; ++mi) {
        acc[mi][ni] = __builtin_amdgcn_mfma_f32_16x16x32_f16(ah[mi], bh, acc[mi][ni], 0, 0, 0);
        acc[mi][ni] = __builtin_amdgcn_mfma_f32_16x16x32_f16(al[mi], bh, acc[mi][ni], 0, 0, 0);
        acc[mi][ni] = __builtin_amdgcn_mfma_f32_16x16x32_f16(ah[mi], bl, acc[mi][ni], 0, 0, 0);
      }
    }
    __syncthreads();
  }

  // ---- epilogue: LDS transpose -> coalesced float4 stores (+ qmean qs) ----
  float* Cl = reinterpret_cast<float*>(lds);   // 32 x 132 f32
  int ri2 = t >> 3, c0 = (t & 7) << 4;
  bool doq = (qpart != nullptr) && (n0 < 256);  // block-uniform
  float qs[16] = {};
#pragma unroll
  for (int mi = 0; mi < 4; ++mi) {
#pragma unroll
    for (int ni = 0; ni < 4; ++ni) {
      int col = wn * 64 + ni * 16 + lr;
#pragma unroll
      for (int r = 0; r < 4; ++r)
        Cl[(wm * 16 + lg * 4 + r) * 132 + col] = acc[mi][ni][r];
    }
    __syncthreads();
    int grow = m0 + (ri2 >> 4) * 64 + mi * 16 + (ri2 & 15);
#pragma unroll
    for (int j = 0; j < 4; ++j) {
      int col = n0 + c0 + j * 4;
      float4 v = *(const float4*)&Cl[ri2 * 132 + c0 + j * 4];
      float4 bb = *(const float4*)&bias[col];
      v.x += bb.x; v.y += bb.y; v.z += bb.z; v.w += bb.w;
      if (col < nelu) {
        v.x = (v.x > 0.f) ? v.x + 1.f : expf(v.x);
        v.y = (v.y > 0.f) ? v.y + 1.f : expf(v.y);
        v.z = (v.z > 0.f) ? v.z + 1.f : expf(v.z);
        v.w = (v.w > 0.f) ? v.w + 1.f : expf(v.w);
      }
      if (doq) {
        qs[j * 4 + 0] += v.x; qs[j * 4 + 1] += v.y;
        qs[j * 4 + 2] += v.z; qs[j * 4 + 3] += v.w;
      }
      *(float4*)&Cm[(size_t)grow * ldc + col] = v;
    }
    __syncthreads();
  }
  if (doq) {
#pragma unroll
    for (int j = 0; j < 4; ++j) {
      float4 w4 = {qs[j*4+0], qs[j*4+1], qs[j*4+2], qs[j*4+3]};
      *(float4*)&Cl[ri2 * 132 + c0 + j * 4] = w4;
    }
    __syncthreads();
    if (t < 128) {
      float ssum = 0.f;
#pragma unroll
      for (int rr = 0; rr < 32; ++rr) ssum += Cl[rr * 132 + t];
      int b_local = m0 >> 12, rowblk = (m0 >> 7) & 31;
      qpart[(size_t)(b_local * 32 + rowblk) * 256 + n0 + t] = ssum;
    }
  }
}

// ---- flash kv: qmean -> chunk scores -> local softmax -> reg-tiled kv ------
// grid (nbh, 8); chunk = 512 n. kvp per (bh,chunk): 1024 kv + 32 km + mx + sum
__global__ __launch_bounds__(256) void k_kvflash(
    const float* __restrict__ qkvo, const float* __restrict__ qpart,
    const float* __restrict__ cosT, const float* __restrict__ sinT,
    float* __restrict__ kvp) {
  __shared__ float qm[32];
  __shared__ float sL[512];
  __shared__ float red[256];
  __shared__ float ktG[4][32][36];   // roped eff*k per group (overlaid later)
  __shared__ float vtG[4][32][36];   // v per group (overlaid later)
  int bh = blockIdx.x, chunk = blockIdx.y;
  int b = bh >> 3, h = bh & 7;
  int t = threadIdx.x;
  int nbase = chunk << 9;

  // phase 0: qmean from GEMM1 partials (fold 1/N and softmax scale)
  if (t < 32) {
    float s = 0.f;
#pragma unroll
    for (int rb = 0; rb < 32; ++rb)
      s += qpart[(size_t)(b * 32 + rb) * 256 + (h << 5) + t];
    qm[t] = s * (1.0f / N) * 0.1767766952966369f;
  }
  __syncthreads();

  // phase A: scores for this chunk's 512 n; chunk max and exp-sum
  float qmr[32];
#pragma unroll
  for (int i = 0; i < 32; ++i) qmr[i] = qm[i];
  float mx = -3.4e38f;
#pragma unroll
  for (int i = 0; i < 2; ++i) {
    int n = nbase + t + i * 256;
    const float* kp = &qkvo[(size_t)(b * N + n) * C4 + 256 + (h << 5)];
    float dot = 0.f;
#pragma unroll
    for (int j = 0; j < 8; ++j) {
      float4 k4 = *(const float4*)(kp + (j << 2));
      dot += k4.x * qmr[j*4] + k4.y * qmr[j*4+1] + k4.z * qmr[j*4+2] + k4.w * qmr[j*4+3];
    }
    sL[t + i * 256] = dot;
    mx = fmaxf(mx, dot);
  }
  red[t] = mx; __syncthreads();
  for (int off = 128; off > 0; off >>= 1) {
    if (t < off) red[t] = fmaxf(red[t], red[t + off]);
    __syncthreads();
  }
  float mx_c = red[0];
  __syncthreads();
  float psum = expf(sL[t] - mx_c) + expf(sL[t + 256] - mx_c);
  red[t] = psum; __syncthreads();
  for (int off = 128; off > 0; off >>= 1) {
    if (t < off) red[t] += red[t + off];
    __syncthreads();
  }
  float sum_c = red[0];

  // phase B: register-tiled kv. group sg owns rows [sg*128, sg*128+128).
  int sg = t >> 6;
  int lane = t & 63;
  int d0 = (lane >> 3) << 2;        // 0..28
  int e0 = (lane & 7) << 2;         // 0..28
  int srow_l = (t >> 1) & 31;       // staging row within group window
  int sdh = t & 1;                  // staging d-half (16 floats)
  float acc[4][4] = {};
  float km16[16] = {};

  for (int s = 0; s < 4; ++s) {
    int nloc = sg * 128 + s * 32 + srow_l;
    int n = nbase + nloc;
    const float* kp = &qkvo[(size_t)(b * N + n) * C4 + 256 + (h << 5) + sdh * 16];
    const float* vp = kp + 256;
    float ef = expf(sL[nloc] - mx_c);
    float kl[16], vl[16];
#pragma unroll
    for (int j4 = 0; j4 < 4; ++j4) {
      float4 k4 = *(const float4*)(kp + (j4 << 2));
      float4 v4 = *(const float4*)(vp + (j4 << 2));
      k4.x *= ef; k4.y *= ef; k4.z *= ef; k4.w *= ef;
      km16[j4*4+0] += k4.x; km16[j4*4+1] += k4.y;
      km16[j4*4+2] += k4.z; km16[j4*4+3] += k4.w;
      kl[j4*4+0] = k4.x; kl[j4*4+1] = k4.y; kl[j4*4+2] = k4.z; kl[j4*4+3] = k4.w;
      vl[j4*4+0] = v4.x; vl[j4*4+1] = v4.y; vl[j4*4+2] = v4.z; vl[j4*4+3] = v4.w;
    }
#pragma unroll
    for (int p = 0; p < 8; ++p) {
      float cc = cosT[(n << 4) + sdh * 8 + p];
      float sn = sinT[(n << 4) + sdh * 8 + p];
      float kr = kl[2*p], ki = kl[2*p+1];
      kl[2*p]   = kr * cc - ki * sn;
      kl[2*p+1] = kr * sn + ki * cc;
    }
#pragma unroll
    for (int j4 = 0; j4 < 4; ++j4) {
      float4 kw = {kl[j4*4+0], kl[j4*4+1], kl[j4*4+2], kl[j4*4+3]};
      float4 vw = {vl[j4*4+0], vl[j4*4+1], vl[j4*4+2], vl[j4*4+3]};
      *(float4*)&ktG[sg][srow_l][sdh*16 + (j4 << 2)] = kw;
      *(float4*)&vtG[sg][srow_l][sdh*16 + (j4 << 2)] = vw;
    }
    __syncthreads();
    __builtin_amdgcn_s_setprio(1);
#pragma unroll
    for (int nn = 0; nn < 32; ++nn) {
      float4 k4 = *(const float4*)&ktG[sg][nn][d0];
      float4 v4 = *(const float4*)&vtG[sg][nn][e0];
      float kv_[4] = {k4.x, k4.y, k4.z, k4.w};
      float vv_[4] = {v4.x, v4.y, v4.z, v4.w};
#pragma unroll
      for (int i = 0; i < 4; ++i)
#pragma unroll
        for (int j = 0; j < 4; ++j)
          acc[i][j] = fmaf(kv_[i], vv_[j], acc[i][j]);
    }
    __builtin_amdgcn_s_setprio(0);
    __syncthreads();
  }

  // merge kv partials (overlay mrg on ktG — all reads done, barrier above)
  float* mrg = &ktG[0][0][0];                  // 4096 floats needed <= 4608
#pragma unroll
  for (int i = 0; i < 4; ++i)
#pragma unroll
    for (int j = 0; j < 4; ++j)
      mrg[sg * 1024 + (d0 + i) * 32 + (e0 + j)] = acc[i][j];
  __syncthreads();
  size_t o = (size_t)(bh * 8 + chunk) * 1058;
  {
    int idx = t << 2;
    float4 r;
    r.x = mrg[idx+0] + mrg[1024+idx+0] + mrg[2048+idx+0] + mrg[3072+idx+0];
    r.y = mrg[idx+1] + mrg[1024+idx+1] + mrg[2048+idx+1] + mrg[3072+idx+1];
    r.z = mrg[idx+2] + mrg[1024+idx+2] + mrg[2048+idx+2] + mrg[3072+idx+2];
    r.w = mrg[idx+3] + mrg[1024+idx+3] + mrg[2048+idx+3] + mrg[3072+idx+3];
    kvp[o + idx + 0] = r.x; kvp[o + idx + 1] = r.y;
    kvp[o + idx + 2] = r.z; kvp[o + idx + 3] = r.w;
  }
  // merge km (overlay on vtG)
  float* kmb = &vtG[0][0][0];                  // [256][16] = 4096 floats
#pragma unroll
  for (int j = 0; j < 16; ++j) kmb[t * 16 + j] = km16[j];
  __syncthreads();
  if (t < 32) {
    int dh = t >> 4, dj = t & 15;
    float ssum = 0.f;
    for (int r = 0; r < 128; ++r) ssum += kmb[((r << 1) + dh) * 16 + dj];
    kvp[o + 1024 + t] = ssum;
  }
  if (t == 0) {
    kvp[o + 1056] = mx_c;
    kvp[o + 1057] = sum_c;
  }
}

// ---- exact log-sum-exp merge of 8 chunks -> kvkm[bh][1056] -----------------
__global__ __launch_bounds__(256) void k_kvfinal(
    const float* __restrict__ kvp, float* __restrict__ kvkm) {
  __shared__ float fc[8];
  int bh = blockIdx.x;
  int t = threadIdx.x;
  if (t == 0) {
    float mxs[8], sums[8];
    float mx = -3.4e38f;
#pragma unroll
    for (int c = 0; c < 8; ++c) {
      size_t o = (size_t)(bh * 8 + c) * 1058;
      mxs[c] = kvp[o + 1056];
      sums[c] = kvp[o + 1057];
      mx = fmaxf(mx, mxs[c]);
    }
    float T = 0.f;
#pragma unroll
    for (int c = 0; c < 8; ++c) T += sums[c] * expf(mxs[c] - mx);
    float invT = 1.0f / T;
#pragma unroll
    for (int c = 0; c < 8; ++c) fc[c] = expf(mxs[c] - mx) * invT;
  }
  __syncthreads();
  float f0 = fc[0], f1 = fc[1], f2 = fc[2], f3 = fc[3];
  float f4 = fc[4], f5 = fc[5], f6 = fc[6], f7 = fc[7];
  for (int j = t; j < 1056; j += 256) {
    size_t o = (size_t)(bh * 8) * 1058 + j;
    float v = kvp[o] * f0 + kvp[o + 1058] * f1 + kvp[o + 2 * 1058] * f2 +
              kvp[o + 3 * 1058] * f3 + kvp[o + 4 * 1058] * f4 +
              kvp[o + 5 * 1058] * f5 + kvp[o + 6 * 1058] * f6 +
              kvp[o + 7 * 1058] * f7;
    kvkm[(size_t)bh * 1056 + j] = v;
  }
}

// -------- depthwise 5x5 conv on v (LEPE) -> staged into d_out rows ----------
__global__ __launch_bounds__(256) void k_lepe(
    const float* __restrict__ qkvo, const float* __restrict__ wgt,
    const float* __restrict__ lb, float* __restrict__ lepe_out, int b0) {
  int blk = blockIdx.x;                        // bpp*64*4
  int b = blk >> 8, rem = blk & 255;
  int y = rem >> 2, x0 = (rem & 3) << 4;       // 16 pixels along x
  int c = threadIdx.x;
  float w[25];
#pragma unroll
  for (int i = 0; i < 25; ++i) w[i] = wgt[c * 25 + i];
  float bias = lb[c];
  float acc[16];
#pragma unroll
  for (int p = 0; p < 16; ++p) acc[p] = bias;
#pragma unroll
  for (int dy = 0; dy < 5; ++dy) {
    int yy = y + dy - 2;
    if (yy < 0 || yy >= IH) continue;
    size_t rowb = (size_t)(b * N + (yy << 6)) * C4 + 512 + c;
#pragma unroll
    for (int dx = 0; dx < 5; ++dx) {
      float wv = w[dy * 5 + dx];
#pragma unroll
      for (int p = 0; p < 16; ++p) {
        int xx = x0 + p + dx - 2;
        if (xx < 0 || xx >= IW) continue;
        acc[p] = fmaf(qkvo[rowb + (size_t)xx * C4], wv, acc[p]);
      }
    }
  }
#pragma unroll
  for (int p = 0; p < 16; ++p)
    lepe_out[(size_t)((b0 + b) * N + (y << 6) + x0 + p) * C + c] = acc[p];
}

// -- opre = ((rope(q) @ kv) * z + lepe) * o, z = 1/(q.kmean+eps), in place ---
__global__ __launch_bounds__(256) void k_out_combine(
    float* __restrict__ qkvo, const float* __restrict__ kvkm,
    const float* __restrict__ cosT, const float* __restrict__ sinT,
    const float* __restrict__ lepe, int b0) {
  __shared__ float kvs[1024];
  __shared__ float kms[32];
  int bh = blockIdx.x, chunk = blockIdx.y;
  int b = bh >> 3, h = bh & 7;
  int t = threadIdx.x;
  reinterpret_cast<float4*>(kvs)[t] =
      reinterpret_cast<const float4*>(&kvkm[(size_t)bh * 1056])[t];
  if (t < 32) kms[t] = kvkm[(size_t)bh * 1056 + 1024 + t];
  __syncthreads();
  int n = (chunk << 8) + t;
  size_t rowbase = (size_t)(b * N + n) * C4;
  float q[32];
#pragma unroll
  for (int i = 0; i < 8; ++i) {
    float4 q4 = *reinterpret_cast<const float4*>(&qkvo[rowbase + (h << 5) + (i << 2)]);
    q[i * 4 + 0] = q4.x; q[i * 4 + 1] = q4.y; q[i * 4 + 2] = q4.z; q[i * 4 + 3] = q4.w;
  }
  float dot = 0.f;
#pragma unroll
  for (int dd = 0; dd < 32; ++dd) dot += q[dd] * kms[dd];
  float zv = 1.0f / (dot + 1e-6f);
  const float* cp = &cosT[n << 4];
  const float* sp = &sinT[n << 4];
#pragma unroll
  for (int j = 0; j < 16; ++j) {
    float cc = cp[j], ss = sp[j];
    float qr = q[2 * j], qi = q[2 * j + 1];
    q[2 * j]     = qr * cc - qi * ss;
    q[2 * j + 1] = qr * ss + qi * cc;
  }
  size_t oc = (size_t)((b0 + b) * N + n) * C + (h << 5);   // lepe rows in d_out
#pragma unroll
  for (int e4 = 0; e4 < 8; ++e4) {
    float ax = 0, ay = 0, az = 0, aw = 0;
#pragma unroll
    for (int dd = 0; dd < 32; ++dd) {
      float4 kv4 = *reinterpret_cast<const float4*>(&kvs[(dd << 5) + (e4 << 2)]);
      float qd = q[dd];
      ax = fmaf(qd, kv4.x, ax); ay = fmaf(qd, kv4.y, ay);
      az = fmaf(qd, kv4.z, az); aw = fmaf(qd, kv4.w, aw);
    }
    float4 lp = *reinterpret_cast<const float4*>(&lepe[oc + (e4 << 2)]);
    float4 ov = *reinterpret_cast<const float4*>(
        &qkvo[rowbase + 768 + (h << 5) + (e4 << 2)]);
    float4 r;
    r.x = (ax * zv + lp.x) * ov.x;
    r.y = (ay * zv + lp.y) * ov.y;
    r.z = (az * zv + lp.z) * ov.z;
    r.w = (aw * zv + lp.w) * ov.w;
    *reinterpret_cast<float4*>(&qkvo[rowbase + (h << 5) + (e4 << 2)]) = r;
  }
}

// ---------------------------------------------------------------------------
static inline size_t ws_bytes_needed(int bpp) {
  size_t pn = (size_t)bpp * N;
  size_t f32c = pn * C4                       // qkvo
              + (size_t)bpp * 32 * 256        // qmean partials
              + (size_t)bpp * NH * 8 * 1058   // kv+km+stats partials
              + (size_t)bpp * NH * 1056       // kvkm
              + (size_t)N * 16 * 2;           // cos/sin
  size_t f16c = (size_t)C * C4 * 2            // wq T splits
              + (size_t)C * C * 2;            // wp T splits
  return f32c * 4 + f16c * 2;
}

extern "C" void kernel_launch(void* const* d_in, const int* in_sizes, int n_in,
                              void* d_out, int out_size, void* d_ws, size_t ws_size,
                              hipStream_t stream) {
  const float* x      = (const float*)d_in[0];
  const float* w_qkvo = (const float*)d_in[1];
  const float* b_qkvo = (const float*)d_in[2];
  const float* lepe_w = (const float*)d_in[3];
  const float* lepe_b = (const float*)d_in[4];
  const float* w_proj = (const float*)d_in[5];
  const float* b_proj = (const float*)d_in[6];
  float* out = (float*)d_out;
  float* ws  = (float*)d_ws;

  int bpp = 2;
  if (ws_bytes_needed(16) <= ws_size) bpp = 16;
  else if (ws_bytes_needed(8) <= ws_size) bpp = 8;
  else if (ws_bytes_needed(4) <= ws_size) bpp = 4;

  size_t pn = (size_t)bpp * N;
  int nbh = bpp * NH;
  float* qkvo  = ws;
  float* qpart = qkvo  + pn * C4;
  float* kvp   = qpart + (size_t)bpp * 32 * 256;
  float* kvkm  = kvp   + (size_t)nbh * 8 * 1058;
  float* cosT  = kvkm  + (size_t)nbh * 1056;
  float* sinT  = cosT  + (size_t)N * 16;
  _Float16* wqh = (_Float16*)(sinT + (size_t)N * 16);
  _Float16* wql = wqh + (size_t)C * C4;
  _Float16* wph = wql + (size_t)C * C4;
  _Float16* wpl = wph + (size_t)C * C;

  k_tables<<<N * 16 / 256, 256, 0, stream>>>(cosT, sinT);
  k_split_wT<<<C4, 256, 0, stream>>>(w_qkvo, C4, wqh, wql);
  k_split_wT<<<C, 256, 0, stream>>>(w_proj, C, wph, wpl);

  for (int b0 = 0; b0 < B; b0 += bpp) {
    // GEMM1: qkvo = x@w_qkvo + b, elu on cols<512, qmean partials fused
    k_gemm_split<<<dim3(pn / 128, C4 / 128), 256, 0, stream>>>(
        x + (size_t)b0 * N * C, C, wqh, wql, b_qkvo, qkvo, C4, 512, qpart);
    k_kvflash<<<dim3(nbh, 8), 256, 0, stream>>>(qkvo, qpart, cosT, sinT, kvp);
    k_kvfinal<<<nbh, 256, 0, stream>>>(kvp, kvkm);
    k_lepe<<<bpp * IH * 4, 256, 0, stream>>>(qkvo, lepe_w, lepe_b, out, b0);
    k_out_combine<<<dim3(nbh, 16), 256, 0, stream>>>(qkvo, kvkm, cosT, sinT, out, b0);
    // GEMM2: out = opre @ w_proj + b (A = f32 opre in qkvo q-slot)
    k_gemm_split<<<dim3(pn / 128, C / 128), 256, 0, stream>>>(
        qkvo, C4, wph, wpl, b_proj, out + (size_t)b0 * N * C, C, 0, nullptr);
  }
}